// Round 2
// baseline (1995.275 us; speedup 1.0000x reference)
//
#include <hip/hip_runtime.h>

#define B_  16
#define T_  2048
#define L_  128
#define M_  256
#define H_  512
#define F_  1024
#define EPS 1e-5f

// LDS: As[64][36] + Bs[64][68] = 6656 floats = 26624 B  (2 blocks/CU)
#define LDA_S 36
#define LDB_S 68
#define SMSZ (64 * LDA_S + 64 * LDB_S)

// ---------------------------------------------------------------------------
// Fast grid barrier (sense-reversing, agent scope). bar[0]=counter, bar[16]=gen
// (separate 64B lines). Requires all blocks co-resident (cooperative launch).
// ---------------------------------------------------------------------------
__device__ __forceinline__ void gbar(unsigned int* bar, int nb) {
    __syncthreads();
    __threadfence();   // release: drain this block's writes (L2 wb for agent scope)
    if (threadIdx.x == 0) {
        unsigned int gen = __hip_atomic_load(bar + 16, __ATOMIC_RELAXED,
                                             __HIP_MEMORY_SCOPE_AGENT);
        unsigned int a = __hip_atomic_fetch_add(bar, 1u, __ATOMIC_RELEASE,
                                                __HIP_MEMORY_SCOPE_AGENT);
        if (a == (unsigned int)(nb - 1)) {
            // last arriver: reset counter, then publish new generation
            __hip_atomic_store(bar, 0u, __ATOMIC_RELAXED,
                               __HIP_MEMORY_SCOPE_AGENT);
            __hip_atomic_fetch_add(bar + 16, 1u, __ATOMIC_RELEASE,
                                   __HIP_MEMORY_SCOPE_AGENT);
        } else {
            while (__hip_atomic_load(bar + 16, __ATOMIC_ACQUIRE,
                                     __HIP_MEMORY_SCOPE_AGENT) == gen)
                __builtin_amdgcn_s_sleep(8);
        }
    }
    __syncthreads();
    __threadfence();   // acquire: invalidate L1/L2 before reading others' data
}

// ---------------------------------------------------------------------------
// A-operand load with source remap.
// amode: 0 = row-major(lda); 1 = gather x[b=r&15][T-1-(r>>4)][:];
//        2 = tree (row -> vin[((r>>4)<<5)+16+(r&15)]);
//        3 = rows 0..M-2 from A, row M-1 from Alast
// ---------------------------------------------------------------------------
__device__ __forceinline__ float4 load_a4(const float* __restrict__ A,
                                          const float* __restrict__ Alast,
                                          int M, int lda, int amode,
                                          int gr, int gk) {
    float4 av = make_float4(0.f, 0.f, 0.f, 0.f);
    if (gr < M) {
        const float* p;
        if (amode == 1)
            p = A + (long)((gr & 15) * T_ + (T_ - 1 - (gr >> 4))) * L_ + gk;
        else if (amode == 2)
            p = A + (long)(((gr >> 4) << 5) + 16 + (gr & 15)) * lda + gk;
        else if (amode == 3 && gr == M - 1)
            p = Alast + gk;
        else
            p = A + (long)gr * lda + gk;
        av = *(const float4*)p;
    }
    return av;
}

// ---------------------------------------------------------------------------
// 32x64 tile GEMM, BK=64, TM=2 TN=4, 256 threads, reg-prefetch pipeline.
// flags: 1 = +bias[c].  amode==2 epilogue adds Add[((r>>4)<<5)+(r&15)].
// ---------------------------------------------------------------------------
__device__ __forceinline__ void gemm_tile(
    float* sm,
    const float* __restrict__ A, const float* __restrict__ Alast,
    const float* __restrict__ Bm, const float* __restrict__ bias,
    const float* __restrict__ Add, float* __restrict__ C,
    int M, int K, int lda, int ldb, int ldc,
    int flags, int amode, int bx, int by)
{
    constexpr int BM = 32, BN = 64, BK = 64, TM = 2, TN = 4;
    float* As = sm;                    // [64][36] transposed A tile
    float* Bs = sm + BK * LDA_S;       // [64][68]
    const int tid = threadIdx.x;
    const int tx = tid & 15;           // BN/TN = 16
    const int ty = tid >> 4;           // 0..15
    const int row0 = by * BM, col0 = bx * BN;

    float4 pa[2], pb[4];
#pragma unroll
    for (int t = 0; t < 2; ++t) {
        int f = tid + t * 256;
        pa[t] = load_a4(A, Alast, M, lda, amode, row0 + (f >> 4), (f & 15) * 4);
    }
#pragma unroll
    for (int t = 0; t < 4; ++t) {
        int f = tid + t * 256;
        pb[t] = *(const float4*)(Bm + (long)(f >> 4) * ldb + col0 + (f & 15) * 4);
    }

    float acc[TM][TN] = {};

    for (int k0 = 0; k0 < K; k0 += BK) {
        __syncthreads();               // prior compute done reading LDS
#pragma unroll
        for (int t = 0; t < 2; ++t) {
            int f = tid + t * 256;
            int arow = f >> 4, kk = (f & 15) * 4;
            As[(kk + 0) * LDA_S + arow] = pa[t].x;
            As[(kk + 1) * LDA_S + arow] = pa[t].y;
            As[(kk + 2) * LDA_S + arow] = pa[t].z;
            As[(kk + 3) * LDA_S + arow] = pa[t].w;
        }
#pragma unroll
        for (int t = 0; t < 4; ++t) {
            int f = tid + t * 256;
            *(float4*)&Bs[(f >> 4) * LDB_S + (f & 15) * 4] = pb[t];
        }
        __syncthreads();
        int kn = k0 + BK;
        if (kn < K) {                  // prefetch next tiles; in flight during FMAs
#pragma unroll
            for (int t = 0; t < 2; ++t) {
                int f = tid + t * 256;
                pa[t] = load_a4(A, Alast, M, lda, amode, row0 + (f >> 4), kn + (f & 15) * 4);
            }
#pragma unroll
            for (int t = 0; t < 4; ++t) {
                int f = tid + t * 256;
                pb[t] = *(const float4*)(Bm + (long)(kn + (f >> 4)) * ldb + col0 + (f & 15) * 4);
            }
        }
#pragma unroll
        for (int kk = 0; kk < BK; ++kk) {
            float ra[TM], rb[TN];
#pragma unroll
            for (int i = 0; i < TM; ++i) ra[i] = As[kk * LDA_S + ty * TM + i];
#pragma unroll
            for (int j = 0; j < TN; ++j) rb[j] = Bs[kk * LDB_S + tx * TN + j];
#pragma unroll
            for (int i = 0; i < TM; ++i)
#pragma unroll
                for (int j = 0; j < TN; ++j)
                    acc[i][j] = fmaf(ra[i], rb[j], acc[i][j]);
        }
    }

#pragma unroll
    for (int i = 0; i < TM; ++i) {
        int r = row0 + ty * TM + i;
        if (r >= M) continue;
#pragma unroll
        for (int j = 0; j < TN; ++j) {
            int c = col0 + tx * TN + j;
            float v = acc[i][j];
            if (flags & 1) v += bias[c];
            if (amode == 2) v += Add[(long)(((r >> 4) << 5) + (r & 15)) * ldc + c];
            C[(long)r * ldc + c] = v;
        }
    }
}

// Dual-job kernel (FALLBACK path): blocks [0,nA) run job A; blocks [nA, ...)
// compute SqOut = SqL @ SqR (512x512x512) for the A-power chain.
__global__ __launch_bounds__(256) void dual(
    const float* A, const float* Alast, const float* Bm, const float* bias,
    const float* Add, float* C, int M, int K, int lda, int ldb, int ldc,
    int flags, int amode, int nbxA, int nA,
    const float* SqL, const float* SqR, float* SqOut)
{
    __shared__ float sm[SMSZ];
    int j = blockIdx.x;
    if (j < nA)
        gemm_tile(sm, A, Alast, Bm, bias, Add, C, M, K, lda, ldb, ldc,
                  flags, amode, j % nbxA, j / nbxA);
    else {
        int s = j - nA;
        gemm_tile(sm, SqL, nullptr, SqR, nullptr, nullptr, SqOut,
                  H_, H_, H_, H_, H_, 0, 0, s % 8, s / 8);
    }
}

// ---------------------------------------------------------------------------
// Tail split-K GEMM: BM=16, BN=64, BK=64, 256 threads, 4 outputs/thread.
// MODE 0: z-GEMM  A = [V1nodes1..3 | x_last] (K=1664), B = [P32;P64;P96;Wr]
// MODE 1: MLP1    A = zn (16x512),  B = W1 (512x1024)
// MODE 2: MLP2    A = hid (16x1024), B = W2 (1024x512)
// Writes partials: parts[kc][16][LDC], kc = jb / nbx.
// ---------------------------------------------------------------------------
#define TLDA 20
#define TLDB 68
#define TSM (64 * TLDA + 64 * TLDB)

template <int MODE>
__device__ __forceinline__ float4 tail_a4(const float* __restrict__ Asrc,
                                          const float* __restrict__ x,
                                          int b, int gk) {
    if (MODE == 0) {
        int seg = gk >> 9;
        if (seg < 3)
            return *(const float4*)(Asrc + (long)((seg + 1) * 16 + b) * H_ + (gk & 511));
        return *(const float4*)(x + ((long)b * T_ + (T_ - 1)) * L_ + (gk - 1536));
    } else if (MODE == 1) {
        return *(const float4*)(Asrc + (long)b * H_ + gk);
    } else {
        return *(const float4*)(Asrc + (long)b * F_ + gk);
    }
}

template <int MODE>
__device__ __forceinline__ float4 tail_b4(const float* __restrict__ P32,
                                          const float* __restrict__ P64,
                                          const float* __restrict__ P96,
                                          const float* __restrict__ WrB,
                                          int kr, int c) {
    if (MODE == 0) {
        const float* p;
        if (kr < 512)       p = P32 + (long)kr * H_;
        else if (kr < 1024) p = P64 + (long)(kr - 512) * H_;
        else if (kr < 1536) p = P96 + (long)(kr - 1024) * H_;
        else                p = WrB + (long)(kr - 1536) * H_;
        return *(const float4*)(p + c);
    } else if (MODE == 1) {
        return *(const float4*)(WrB + (long)kr * F_ + c);
    } else {
        return *(const float4*)(WrB + (long)kr * H_ + c);
    }
}

template <int MODE>
__device__ __forceinline__ void tail_job(
    float* sm,
    const float* __restrict__ Asrc, const float* __restrict__ x,
    const float* __restrict__ P32, const float* __restrict__ P64,
    const float* __restrict__ P96, const float* __restrict__ WrB,
    float* __restrict__ parts, int nbx, int kLen, int jb)
{
    constexpr int LDC = (MODE == 1) ? F_ : H_;
    float* As = sm;                    // [64][20] transposed (A[k][row])
    float* Bs = sm + 64 * TLDA;        // [64][68]
    const int tid = threadIdx.x;
    const int tx = tid & 15, ty = tid >> 4;      // ty = row 0..15
    const int kc = jb / nbx;
    const int col0 = (jb % nbx) * 64;
    const int kOff = kc * kLen;

    float4 pa, pb[4];
    {
        int gk = kOff + (tid & 15) * 4;
        pa = tail_a4<MODE>(Asrc, x, tid >> 4, gk);
#pragma unroll
        for (int t = 0; t < 4; ++t) {
            int f = tid + t * 256;
            pb[t] = tail_b4<MODE>(P32, P64, P96, WrB, kOff + (f >> 4), col0 + (f & 15) * 4);
        }
    }

    float acc[4] = {};
    for (int k0 = kOff; k0 < kOff + kLen; k0 += 64) {
        __syncthreads();
        {
            int arow = tid >> 4, kk = (tid & 15) * 4;
            As[(kk + 0) * TLDA + arow] = pa.x;
            As[(kk + 1) * TLDA + arow] = pa.y;
            As[(kk + 2) * TLDA + arow] = pa.z;
            As[(kk + 3) * TLDA + arow] = pa.w;
        }
#pragma unroll
        for (int t = 0; t < 4; ++t) {
            int f = tid + t * 256;
            *(float4*)&Bs[(f >> 4) * TLDB + (f & 15) * 4] = pb[t];
        }
        __syncthreads();
        int kn = k0 + 64;
        if (kn < kOff + kLen) {
            pa = tail_a4<MODE>(Asrc, x, tid >> 4, kn + (tid & 15) * 4);
#pragma unroll
            for (int t = 0; t < 4; ++t) {
                int f = tid + t * 256;
                pb[t] = tail_b4<MODE>(P32, P64, P96, WrB, kn + (f >> 4), col0 + (f & 15) * 4);
            }
        }
#pragma unroll
        for (int kk = 0; kk < 64; ++kk) {
            float ra = As[kk * TLDA + ty];
            float4 rb = *(float4*)&Bs[kk * TLDB + tx * 4];
            acc[0] = fmaf(ra, rb.x, acc[0]);
            acc[1] = fmaf(ra, rb.y, acc[1]);
            acc[2] = fmaf(ra, rb.z, acc[2]);
            acc[3] = fmaf(ra, rb.w, acc[3]);
        }
    }

    float* dst = parts + (long)kc * 16 * LDC + (long)ty * LDC + col0 + tx * 4;
    *(float4*)dst = make_float4(acc[0], acc[1], acc[2], acc[3]);
}

template <int MODE>
__global__ __launch_bounds__(256) void tailgemm(
    const float* __restrict__ Asrc, const float* __restrict__ x,
    const float* __restrict__ P32, const float* __restrict__ P64,
    const float* __restrict__ P96, const float* __restrict__ WrB,
    float* __restrict__ parts, int nbx, int kLen)
{
    __shared__ float sm[TSM];
    tail_job<MODE>(sm, Asrc, x, P32, P64, P96, WrB, parts, nbx, kLen, blockIdx.x);
}

// z = node0 + br + sum(zparts); LayerNorm -> zn.  (job b = batch row)
__device__ __forceinline__ void zln_job(
    float* red, const float* __restrict__ V1, const float* __restrict__ zparts,
    const float* __restrict__ br, const float* __restrict__ lng,
    const float* __restrict__ lnb, float* __restrict__ zn, int b)
{
    const int tid = threadIdx.x;
    float z[2];
#pragma unroll
    for (int jj = 0; jj < 2; ++jj) {
        int c = tid + jj * 256;
        float s = V1[(long)b * H_ + c] + br[c];      // node0 row
#pragma unroll
        for (int kc = 0; kc < 13; ++kc)
            s += zparts[(long)kc * 16 * H_ + (long)b * H_ + c];
        z[jj] = s;
    }
    float s1 = z[0] + z[1];
    float s2 = z[0] * z[0] + z[1] * z[1];
#pragma unroll
    for (int off = 32; off > 0; off >>= 1) {
        s1 += __shfl_down(s1, off, 64);
        s2 += __shfl_down(s2, off, 64);
    }
    int wid = tid >> 6, lane = tid & 63;
    __syncthreads();
    if (lane == 0) { red[wid] = s1; red[4 + wid] = s2; }
    __syncthreads();
    float S1 = red[0] + red[1] + red[2] + red[3];
    float S2 = red[4] + red[5] + red[6] + red[7];
    float mu  = S1 * (1.0f / H_);
    float var = S2 * (1.0f / H_) - mu * mu;
    float rs  = rsqrtf(var + EPS);
#pragma unroll
    for (int jj = 0; jj < 2; ++jj) {
        int c = tid + jj * 256;
        zn[(long)b * H_ + c] = (z[jj] - mu) * rs * lng[c] + lnb[c];
    }
}

__global__ __launch_bounds__(256) void zlnred(
    const float* __restrict__ V1, const float* __restrict__ zparts,
    const float* __restrict__ br, const float* __restrict__ lng,
    const float* __restrict__ lnb, float* __restrict__ zn)
{
    __shared__ float red[8];
    zln_job(red, V1, zparts, br, lng, lnb, zn, blockIdx.x);
}

// hid = relu(b1 + sum_{kc<4} h1p[kc])
__device__ __forceinline__ void hred_job(const float* __restrict__ h1p,
                                         const float* __restrict__ b1,
                                         float* __restrict__ hid, int j)
{
    int b = j >> 2;
    int c = (j & 3) * 256 + threadIdx.x;
    float s = b1[c];
#pragma unroll
    for (int kc = 0; kc < 4; ++kc)
        s += h1p[(long)kc * 16 * F_ + (long)b * F_ + c];
    hid[(long)b * F_ + c] = fmaxf(s, 0.f);
}

__global__ __launch_bounds__(256) void hred(
    const float* __restrict__ h1p, const float* __restrict__ b1,
    float* __restrict__ hid)
{
    hred_job(h1p, b1, hid, blockIdx.x);
}

// out = b2 + sum_{kc<8} op[kc]
__device__ __forceinline__ void ored_job(const float* __restrict__ op,
                                         const float* __restrict__ b2,
                                         float* __restrict__ out, int j)
{
    int b = j >> 1;
    int c = (j & 1) * 256 + threadIdx.x;
    float s = b2[c];
#pragma unroll
    for (int kc = 0; kc < 8; ++kc)
        s += op[(long)kc * 16 * H_ + (long)b * H_ + c];
    out[(long)b * H_ + c] = s;
}

__global__ __launch_bounds__(256) void ored(
    const float* __restrict__ op, const float* __restrict__ b2,
    float* __restrict__ out)
{
    ored_job(op, b2, out, blockIdx.x);
}

// ---------------------------------------------------------------------------
// Persistent cooperative mega-kernel with FAST custom grid barrier.
// 512 blocks x 256 threads, 2 blocks/CU co-resident (LDS 26.6KB x2, VGPR 88).
// ---------------------------------------------------------------------------
__global__ __launch_bounds__(256, 2) void mega(
    const float* __restrict__ x, const float* __restrict__ We,
    const float* __restrict__ be, const float* __restrict__ Wb,
    const float* __restrict__ Amat, const float* __restrict__ Wr,
    const float* __restrict__ br, const float* __restrict__ lng,
    const float* __restrict__ lnb, const float* __restrict__ W1,
    const float* __restrict__ b1, const float* __restrict__ W2,
    const float* __restrict__ b2, float* __restrict__ out,
    float* __restrict__ ws, unsigned int* bar)
{
    __shared__ float sm[SMSZ];
    float* Wc  = ws;                         // 129 x 512
    float* V0  = Wc + 129 * H_;              // 2048 x 512
    float* V1  = V0 + 2048 * H_;             // 1024 x 512
    float* P2  = V1 + 1024 * H_;             // A^2
    float* P4  = P2 + H_ * H_;               // A^4
    float* P8  = P4 + H_ * H_;               // A^8
    float* P16 = P8 + H_ * H_;               // A^16
    float* P32 = P16 + H_ * H_;              // A^32
    float* P64 = P32 + H_ * H_;              // A^64
    float* P96 = P64 + H_ * H_;              // A^96
    float* zn  = P96 + H_ * H_;              // 16 x 512
    float* hid = zn + B_ * H_;               // 16 x 1024
    float* zp  = hid + B_ * F_;              // 13 x 16 x 512
    float* h1p = zp + 13 * B_ * H_;          // 4 x 16 x 1024
    float* op  = h1p + 4 * B_ * F_;          // 8 x 16 x 512

    const int bid = blockIdx.x;
    const int NB  = gridDim.x;

    // S0: Wc = [We;be]@Wb (40 jobs) || A^2 (128 jobs)
    for (int j = bid; j < 168; j += NB) {
        if (j < 40)
            gemm_tile(sm, We, be, Wb, nullptr, nullptr, Wc,
                      129, M_, M_, H_, H_, 0, 3, j & 7, j >> 3);
        else {
            int s = j - 40;
            gemm_tile(sm, Amat, nullptr, Amat, nullptr, nullptr, P2,
                      H_, H_, H_, H_, H_, 0, 0, s & 7, s >> 3);
        }
    }
    gbar(bar, NB);

    // S1: V0 = gather(x)@Wc + bc (512 jobs) || A^4 (128)
    for (int j = bid; j < 640; j += NB) {
        if (j < 512)
            gemm_tile(sm, x, nullptr, Wc, Wc + 128 * H_, nullptr, V0,
                      2048, L_, L_, H_, H_, 1, 1, j & 7, j >> 3);
        else {
            int s = j - 512;
            gemm_tile(sm, P2, nullptr, P2, nullptr, nullptr, P4,
                      H_, H_, H_, H_, H_, 0, 0, s & 7, s >> 3);
        }
    }
    gbar(bar, NB);

    // S2: tree L1: V1 = comb(V0, A), 1024 rows (256) || A^8 (128)
    for (int j = bid; j < 384; j += NB) {
        if (j < 256)
            gemm_tile(sm, V0, nullptr, Amat, nullptr, V0, V1,
                      1024, H_, H_, H_, H_, 0, 2, j & 7, j >> 3);
        else {
            int s = j - 256;
            gemm_tile(sm, P4, nullptr, P4, nullptr, nullptr, P8,
                      H_, H_, H_, H_, H_, 0, 0, s & 7, s >> 3);
        }
    }
    gbar(bar, NB);

    // S3: tree L2: V0 = comb(V1, A^2), 512 rows (128) || A^16 (128)
    for (int j = bid; j < 256; j += NB) {
        if (j < 128)
            gemm_tile(sm, V1, nullptr, P2, nullptr, V1, V0,
                      512, H_, H_, H_, H_, 0, 2, j & 7, j >> 3);
        else {
            int s = j - 128;
            gemm_tile(sm, P8, nullptr, P8, nullptr, nullptr, P16,
                      H_, H_, H_, H_, H_, 0, 0, s & 7, s >> 3);
        }
    }
    gbar(bar, NB);

    // S4: tree L3: V1 = comb(V0, A^4), 256 rows (64) || A^32 (128)
    for (int j = bid; j < 192; j += NB) {
        if (j < 64)
            gemm_tile(sm, V0, nullptr, P4, nullptr, V0, V1,
                      256, H_, H_, H_, H_, 0, 2, j & 7, j >> 3);
        else {
            int s = j - 64;
            gemm_tile(sm, P16, nullptr, P16, nullptr, nullptr, P32,
                      H_, H_, H_, H_, H_, 0, 0, s & 7, s >> 3);
        }
    }
    gbar(bar, NB);

    // S5: tree L4: V0 = comb(V1, A^8), 128 rows (32) || A^64 (128)
    for (int j = bid; j < 160; j += NB) {
        if (j < 32)
            gemm_tile(sm, V1, nullptr, P8, nullptr, V1, V0,
                      128, H_, H_, H_, H_, 0, 2, j & 7, j >> 3);
        else {
            int s = j - 32;
            gemm_tile(sm, P32, nullptr, P32, nullptr, nullptr, P64,
                      H_, H_, H_, H_, H_, 0, 0, s & 7, s >> 3);
        }
    }
    gbar(bar, NB);

    // S6: tree L5: V1 = comb(V0, A^16), 64 rows (16) || A^96 = A^32*A^64 (128)
    for (int j = bid; j < 144; j += NB) {
        if (j < 16)
            gemm_tile(sm, V0, nullptr, P16, nullptr, V0, V1,
                      64, H_, H_, H_, H_, 0, 2, j & 7, j >> 3);
        else {
            int s = j - 16;
            gemm_tile(sm, P32, nullptr, P64, nullptr, nullptr, P96,
                      H_, H_, H_, H_, H_, 0, 0, s & 7, s >> 3);
        }
    }
    gbar(bar, NB);

    // S7: z-partials (K=1664, 13 chunks x 8 col tiles = 104 jobs)
    for (int j = bid; j < 104; j += NB)
        tail_job<0>(sm, V1, x, P32, P64, P96, Wr, zp, 8, 128, j);
    gbar(bar, NB);

    // S7b: z reduce + LayerNorm -> zn (16 jobs)
    for (int j = bid; j < 16; j += NB)
        zln_job(sm, V1, zp, br, lng, lnb, zn, j);
    gbar(bar, NB);

    // S8: MLP1 partials (64 jobs)
    for (int j = bid; j < 64; j += NB)
        tail_job<1>(sm, zn, nullptr, nullptr, nullptr, nullptr, W1, h1p, 16, 128, j);
    gbar(bar, NB);

    // S8b: relu-reduce -> hid (64 jobs)
    for (int j = bid; j < 64; j += NB)
        hred_job(h1p, b1, hid, j);
    gbar(bar, NB);

    // S9: MLP2 partials (64 jobs)
    for (int j = bid; j < 64; j += NB)
        tail_job<2>(sm, hid, nullptr, nullptr, nullptr, nullptr, W2, op, 8, 128, j);
    gbar(bar, NB);

    // S9b: reduce -> out (32 jobs)
    for (int j = bid; j < 32; j += NB)
        ored_job(op, b2, out, j);
}

// ---------------------------------------------------------------------------
extern "C" void kernel_launch(void* const* d_in, const int* in_sizes, int n_in,
                              void* d_out, int out_size, void* d_ws, size_t ws_size,
                              hipStream_t stream) {
    const float* x    = (const float*)d_in[0];
    const float* We   = (const float*)d_in[1];
    const float* be   = (const float*)d_in[2];
    const float* Wb   = (const float*)d_in[3];
    const float* Amat = (const float*)d_in[4];
    const float* Wr   = (const float*)d_in[5];
    const float* br   = (const float*)d_in[6];
    const float* lng  = (const float*)d_in[7];
    const float* lnb  = (const float*)d_in[8];
    const float* W1   = (const float*)d_in[9];
    const float* b1   = (const float*)d_in[10];
    const float* W2   = (const float*)d_in[11];
    const float* b2   = (const float*)d_in[12];
    float* out = (float*)d_out;
    float* ws  = (float*)d_ws;

    // barrier state: last 256B of workspace (far from the ~15MB of live data)
    unsigned int* bar =
        (unsigned int*)((char*)d_ws + ((ws_size - 256) & ~(size_t)255));
    hipMemsetAsync(bar, 0, 256, stream);

    // ---- cooperative mega-kernel path ----
    void* kargs[] = {
        (void*)&x,   (void*)&We,  (void*)&be,  (void*)&Wb,  (void*)&Amat,
        (void*)&Wr,  (void*)&br,  (void*)&lng, (void*)&lnb, (void*)&W1,
        (void*)&b1,  (void*)&W2,  (void*)&b2,  (void*)&out, (void*)&ws,
        (void*)&bar };

    hipError_t e = hipLaunchCooperativeKernel((const void*)mega, dim3(512),
                                              dim3(256), kargs, 0, stream);
    if (e != hipSuccess) {
        (void)hipGetLastError();
        e = hipLaunchCooperativeKernel((const void*)mega, dim3(256),
                                       dim3(256), kargs, 0, stream);
    }
    if (e == hipSuccess) return;
    (void)hipGetLastError();

    // ---- fallback: original 13-launch sequence ----
    float* Wc  = ws;
    float* V0  = Wc + 129 * H_;
    float* V1  = V0 + 2048 * H_;
    float* P2  = V1 + 1024 * H_;
    float* P4  = P2 + H_ * H_;
    float* P8  = P4 + H_ * H_;
    float* P16 = P8 + H_ * H_;
    float* P32 = P16 + H_ * H_;
    float* P64 = P32 + H_ * H_;
    float* P96 = P64 + H_ * H_;
    float* zn  = P96 + H_ * H_;
    float* hid = zn + B_ * H_;
    float* zp  = hid + B_ * F_;
    float* h1p = zp + 13 * B_ * H_;
    float* op  = h1p + 4 * B_ * F_;

    dual<<<168, 256, 0, stream>>>(We, be, Wb, nullptr, nullptr, Wc,
                                  129, M_, M_, H_, H_, 0, 3, 8, 40,
                                  Amat, Amat, P2);
    dual<<<640, 256, 0, stream>>>(x, nullptr, Wc, Wc + 128 * H_, nullptr, V0,
                                  2048, L_, L_, H_, H_, 1, 1, 8, 512,
                                  P2, P2, P4);
    dual<<<384, 256, 0, stream>>>(V0, nullptr, Amat, nullptr, V0, V1,
                                  1024, H_, H_, H_, H_, 0, 2, 8, 256,
                                  P4, P4, P8);
    dual<<<256, 256, 0, stream>>>(V1, nullptr, P2, nullptr, V1, V0,
                                  512, H_, H_, H_, H_, 0, 2, 8, 128,
                                  P8, P8, P16);
    dual<<<192, 256, 0, stream>>>(V0, nullptr, P4, nullptr, V0, V1,
                                  256, H_, H_, H_, H_, 0, 2, 8, 64,
                                  P16, P16, P32);
    dual<<<160, 256, 0, stream>>>(V1, nullptr, P8, nullptr, V1, V0,
                                  128, H_, H_, H_, H_, 0, 2, 8, 32,
                                  P32, P32, P64);
    dual<<<144, 256, 0, stream>>>(V0, nullptr, P16, nullptr, V0, V1,
                                  64, H_, H_, H_, H_, 0, 2, 8, 16,
                                  P32, P64, P96);
    tailgemm<0><<<104, 256, 0, stream>>>(V1, x, P32, P64, P96, Wr, zp, 8, 128);
    zlnred<<<16, 256, 0, stream>>>(V1, zp, br, lng, lnb, zn);
    tailgemm<1><<<64, 256, 0, stream>>>(zn, nullptr, nullptr, nullptr, nullptr,
                                        W1, h1p, 16, 128);
    hred<<<64, 256, 0, stream>>>(h1p, b1, hid);
    tailgemm<2><<<64, 256, 0, stream>>>(hid, nullptr, nullptr, nullptr, nullptr,
                                        W2, op, 8, 128);
    ored<<<32, 256, 0, stream>>>(op, b2, out);
}

// Round 3
// 1833.892 us; speedup vs baseline: 1.0880x; 1.0880x over previous
//
#include <hip/hip_runtime.h>

#define B_  16
#define T_  2048
#define L_  128
#define M_  256
#define H_  512
#define F_  1024
#define EPS 1e-5f

// LDS: As[64][36] + Bs[64][68] = 6656 floats = 26624 B  (2 blocks/CU)
#define LDA_S 36
#define LDB_S 68
#define SMSZ (64 * LDA_S + 64 * LDB_S)

// ---------------------------------------------------------------------------
// Two-level grid barrier (sense-reversing).
// Layout (uint index, 64B-line separated):
//   bar[g*16], g=0..7 : per-group arrival counters (group = bid & 7)
//   bar[128]          : group-completion counter
//   bar[144]          : generation word
// Rationale: a single arrival counter serializes 512 cross-XCD atomic RMWs
// (~300ns ownership migration each ~= 150us, measured round 2). Two levels
// give 8 parallel RMW streams (intra-group mostly same-XCD under round-robin
// block placement) + 8 cross-XCD RMWs. Correct for any block->XCD mapping.
// ---------------------------------------------------------------------------
__device__ __forceinline__ void gbar(unsigned int* bar, int nb) {
    __syncthreads();
    __threadfence();   // release: drain stores + L2 writeback (agent scope)
    if (threadIdx.x == 0) {
        const int g = blockIdx.x & 7;
        const unsigned int nInG = (unsigned int)(nb >> 3);   // nb % 8 == 0
        unsigned int gen = __hip_atomic_load(bar + 144, __ATOMIC_RELAXED,
                                             __HIP_MEMORY_SCOPE_AGENT);
        unsigned int a = __hip_atomic_fetch_add(bar + g * 16, 1u,
                                                __ATOMIC_RELAXED,
                                                __HIP_MEMORY_SCOPE_AGENT);
        if (a == nInG - 1) {
            // last arriver in group: reset group counter, bump global
            __hip_atomic_store(bar + g * 16, 0u, __ATOMIC_RELAXED,
                               __HIP_MEMORY_SCOPE_AGENT);
            unsigned int b = __hip_atomic_fetch_add(bar + 128, 1u,
                                                    __ATOMIC_RELAXED,
                                                    __HIP_MEMORY_SCOPE_AGENT);
            if (b == 7u) {
                __hip_atomic_store(bar + 128, 0u, __ATOMIC_RELAXED,
                                   __HIP_MEMORY_SCOPE_AGENT);
                __hip_atomic_fetch_add(bar + 144, 1u, __ATOMIC_RELEASE,
                                       __HIP_MEMORY_SCOPE_AGENT);
            }
        }
        while (__hip_atomic_load(bar + 144, __ATOMIC_ACQUIRE,
                                 __HIP_MEMORY_SCOPE_AGENT) == gen)
            __builtin_amdgcn_s_sleep(1);
    }
    __syncthreads();
    __threadfence();   // acquire: invalidate caches before reading peers' data
}

// ---------------------------------------------------------------------------
// A-operand load with source remap.
// amode: 0 = row-major(lda); 1 = gather x[b=r&15][T-1-(r>>4)][:];
//        2 = tree (row -> vin[((r>>4)<<5)+16+(r&15)]);
//        3 = rows 0..M-2 from A, row M-1 from Alast
// ---------------------------------------------------------------------------
__device__ __forceinline__ float4 load_a4(const float* __restrict__ A,
                                          const float* __restrict__ Alast,
                                          int M, int lda, int amode,
                                          int gr, int gk) {
    float4 av = make_float4(0.f, 0.f, 0.f, 0.f);
    if (gr < M) {
        const float* p;
        if (amode == 1)
            p = A + (long)((gr & 15) * T_ + (T_ - 1 - (gr >> 4))) * L_ + gk;
        else if (amode == 2)
            p = A + (long)(((gr >> 4) << 5) + 16 + (gr & 15)) * lda + gk;
        else if (amode == 3 && gr == M - 1)
            p = Alast + gk;
        else
            p = A + (long)gr * lda + gk;
        av = *(const float4*)p;
    }
    return av;
}

// ---------------------------------------------------------------------------
// 32x64 tile GEMM, BK=64, TM=2 TN=4, 256 threads, reg-prefetch pipeline.
// flags: 1 = +bias[c].  amode==2 epilogue adds Add[((r>>4)<<5)+(r&15)].
// ---------------------------------------------------------------------------
__device__ __forceinline__ void gemm_tile(
    float* sm,
    const float* __restrict__ A, const float* __restrict__ Alast,
    const float* __restrict__ Bm, const float* __restrict__ bias,
    const float* __restrict__ Add, float* __restrict__ C,
    int M, int K, int lda, int ldb, int ldc,
    int flags, int amode, int bx, int by)
{
    constexpr int BM = 32, BN = 64, BK = 64, TM = 2, TN = 4;
    float* As = sm;                    // [64][36] transposed A tile
    float* Bs = sm + BK * LDA_S;       // [64][68]
    const int tid = threadIdx.x;
    const int tx = tid & 15;           // BN/TN = 16
    const int ty = tid >> 4;           // 0..15
    const int row0 = by * BM, col0 = bx * BN;

    float4 pa[2], pb[4];
#pragma unroll
    for (int t = 0; t < 2; ++t) {
        int f = tid + t * 256;
        pa[t] = load_a4(A, Alast, M, lda, amode, row0 + (f >> 4), (f & 15) * 4);
    }
#pragma unroll
    for (int t = 0; t < 4; ++t) {
        int f = tid + t * 256;
        pb[t] = *(const float4*)(Bm + (long)(f >> 4) * ldb + col0 + (f & 15) * 4);
    }

    float acc[TM][TN] = {};

    for (int k0 = 0; k0 < K; k0 += BK) {
        __syncthreads();               // prior compute done reading LDS
#pragma unroll
        for (int t = 0; t < 2; ++t) {
            int f = tid + t * 256;
            int arow = f >> 4, kk = (f & 15) * 4;
            As[(kk + 0) * LDA_S + arow] = pa[t].x;
            As[(kk + 1) * LDA_S + arow] = pa[t].y;
            As[(kk + 2) * LDA_S + arow] = pa[t].z;
            As[(kk + 3) * LDA_S + arow] = pa[t].w;
        }
#pragma unroll
        for (int t = 0; t < 4; ++t) {
            int f = tid + t * 256;
            *(float4*)&Bs[(f >> 4) * LDB_S + (f & 15) * 4] = pb[t];
        }
        __syncthreads();
        int kn = k0 + BK;
        if (kn < K) {                  // prefetch next tiles; in flight during FMAs
#pragma unroll
            for (int t = 0; t < 2; ++t) {
                int f = tid + t * 256;
                pa[t] = load_a4(A, Alast, M, lda, amode, row0 + (f >> 4), kn + (f & 15) * 4);
            }
#pragma unroll
            for (int t = 0; t < 4; ++t) {
                int f = tid + t * 256;
                pb[t] = *(const float4*)(Bm + (long)(kn + (f >> 4)) * ldb + col0 + (f & 15) * 4);
            }
        }
#pragma unroll
        for (int kk = 0; kk < BK; ++kk) {
            float ra[TM], rb[TN];
#pragma unroll
            for (int i = 0; i < TM; ++i) ra[i] = As[kk * LDA_S + ty * TM + i];
#pragma unroll
            for (int j = 0; j < TN; ++j) rb[j] = Bs[kk * LDB_S + tx * TN + j];
#pragma unroll
            for (int i = 0; i < TM; ++i)
#pragma unroll
                for (int j = 0; j < TN; ++j)
                    acc[i][j] = fmaf(ra[i], rb[j], acc[i][j]);
        }
    }

#pragma unroll
    for (int i = 0; i < TM; ++i) {
        int r = row0 + ty * TM + i;
        if (r >= M) continue;
#pragma unroll
        for (int j = 0; j < TN; ++j) {
            int c = col0 + tx * TN + j;
            float v = acc[i][j];
            if (flags & 1) v += bias[c];
            if (amode == 2) v += Add[(long)(((r >> 4) << 5) + (r & 15)) * ldc + c];
            C[(long)r * ldc + c] = v;
        }
    }
}

// Dual-job kernel (FALLBACK path): blocks [0,nA) run job A; blocks [nA, ...)
// compute SqOut = SqL @ SqR (512x512x512) for the A-power chain.
__global__ __launch_bounds__(256) void dual(
    const float* A, const float* Alast, const float* Bm, const float* bias,
    const float* Add, float* C, int M, int K, int lda, int ldb, int ldc,
    int flags, int amode, int nbxA, int nA,
    const float* SqL, const float* SqR, float* SqOut)
{
    __shared__ float sm[SMSZ];
    int j = blockIdx.x;
    if (j < nA)
        gemm_tile(sm, A, Alast, Bm, bias, Add, C, M, K, lda, ldb, ldc,
                  flags, amode, j % nbxA, j / nbxA);
    else {
        int s = j - nA;
        gemm_tile(sm, SqL, nullptr, SqR, nullptr, nullptr, SqOut,
                  H_, H_, H_, H_, H_, 0, 0, s % 8, s / 8);
    }
}

// ---------------------------------------------------------------------------
// Tail split-K GEMM: BM=16, BN=64, BK=64, 256 threads, 4 outputs/thread.
// MODE 0: z-GEMM  A = [V1nodes1..3 | x_last] (K=1664), B = [P32;P64;P96;Wr]
// MODE 1: MLP1    A = zn (16x512),  B = W1 (512x1024)
// MODE 2: MLP2    A = hid (16x1024), B = W2 (1024x512)
// Writes partials: parts[kc][16][LDC], kc = jb / nbx.
// ---------------------------------------------------------------------------
#define TLDA 20
#define TLDB 68
#define TSM (64 * TLDA + 64 * TLDB)

template <int MODE>
__device__ __forceinline__ float4 tail_a4(const float* __restrict__ Asrc,
                                          const float* __restrict__ x,
                                          int b, int gk) {
    if (MODE == 0) {
        int seg = gk >> 9;
        if (seg < 3)
            return *(const float4*)(Asrc + (long)((seg + 1) * 16 + b) * H_ + (gk & 511));
        return *(const float4*)(x + ((long)b * T_ + (T_ - 1)) * L_ + (gk - 1536));
    } else if (MODE == 1) {
        return *(const float4*)(Asrc + (long)b * H_ + gk);
    } else {
        return *(const float4*)(Asrc + (long)b * F_ + gk);
    }
}

template <int MODE>
__device__ __forceinline__ float4 tail_b4(const float* __restrict__ P32,
                                          const float* __restrict__ P64,
                                          const float* __restrict__ P96,
                                          const float* __restrict__ WrB,
                                          int kr, int c) {
    if (MODE == 0) {
        const float* p;
        if (kr < 512)       p = P32 + (long)kr * H_;
        else if (kr < 1024) p = P64 + (long)(kr - 512) * H_;
        else if (kr < 1536) p = P96 + (long)(kr - 1024) * H_;
        else                p = WrB + (long)(kr - 1536) * H_;
        return *(const float4*)(p + c);
    } else if (MODE == 1) {
        return *(const float4*)(WrB + (long)kr * F_ + c);
    } else {
        return *(const float4*)(WrB + (long)kr * H_ + c);
    }
}

template <int MODE>
__device__ __forceinline__ void tail_job(
    float* sm,
    const float* __restrict__ Asrc, const float* __restrict__ x,
    const float* __restrict__ P32, const float* __restrict__ P64,
    const float* __restrict__ P96, const float* __restrict__ WrB,
    float* __restrict__ parts, int nbx, int kLen, int jb)
{
    constexpr int LDC = (MODE == 1) ? F_ : H_;
    float* As = sm;                    // [64][20] transposed (A[k][row])
    float* Bs = sm + 64 * TLDA;        // [64][68]
    const int tid = threadIdx.x;
    const int tx = tid & 15, ty = tid >> 4;      // ty = row 0..15
    const int kc = jb / nbx;
    const int col0 = (jb % nbx) * 64;
    const int kOff = kc * kLen;

    float4 pa, pb[4];
    {
        int gk = kOff + (tid & 15) * 4;
        pa = tail_a4<MODE>(Asrc, x, tid >> 4, gk);
#pragma unroll
        for (int t = 0; t < 4; ++t) {
            int f = tid + t * 256;
            pb[t] = tail_b4<MODE>(P32, P64, P96, WrB, kOff + (f >> 4), col0 + (f & 15) * 4);
        }
    }

    float acc[4] = {};
    for (int k0 = kOff; k0 < kOff + kLen; k0 += 64) {
        __syncthreads();
        {
            int arow = tid >> 4, kk = (tid & 15) * 4;
            As[(kk + 0) * TLDA + arow] = pa.x;
            As[(kk + 1) * TLDA + arow] = pa.y;
            As[(kk + 2) * TLDA + arow] = pa.z;
            As[(kk + 3) * TLDA + arow] = pa.w;
        }
#pragma unroll
        for (int t = 0; t < 4; ++t) {
            int f = tid + t * 256;
            *(float4*)&Bs[(f >> 4) * TLDB + (f & 15) * 4] = pb[t];
        }
        __syncthreads();
        int kn = k0 + 64;
        if (kn < kOff + kLen) {
            pa = tail_a4<MODE>(Asrc, x, tid >> 4, kn + (tid & 15) * 4);
#pragma unroll
            for (int t = 0; t < 4; ++t) {
                int f = tid + t * 256;
                pb[t] = tail_b4<MODE>(P32, P64, P96, WrB, kn + (f >> 4), col0 + (f & 15) * 4);
            }
        }
#pragma unroll
        for (int kk = 0; kk < 64; ++kk) {
            float ra = As[kk * TLDA + ty];
            float4 rb = *(float4*)&Bs[kk * TLDB + tx * 4];
            acc[0] = fmaf(ra, rb.x, acc[0]);
            acc[1] = fmaf(ra, rb.y, acc[1]);
            acc[2] = fmaf(ra, rb.z, acc[2]);
            acc[3] = fmaf(ra, rb.w, acc[3]);
        }
    }

    float* dst = parts + (long)kc * 16 * LDC + (long)ty * LDC + col0 + tx * 4;
    *(float4*)dst = make_float4(acc[0], acc[1], acc[2], acc[3]);
}

template <int MODE>
__global__ __launch_bounds__(256) void tailgemm(
    const float* __restrict__ Asrc, const float* __restrict__ x,
    const float* __restrict__ P32, const float* __restrict__ P64,
    const float* __restrict__ P96, const float* __restrict__ WrB,
    float* __restrict__ parts, int nbx, int kLen)
{
    __shared__ float sm[TSM];
    tail_job<MODE>(sm, Asrc, x, P32, P64, P96, WrB, parts, nbx, kLen, blockIdx.x);
}

// z = node0 + br + sum(zparts); LayerNorm -> zn.  (job b = batch row)
__device__ __forceinline__ void zln_job(
    float* red, const float* __restrict__ V1, const float* __restrict__ zparts,
    const float* __restrict__ br, const float* __restrict__ lng,
    const float* __restrict__ lnb, float* __restrict__ zn, int b)
{
    const int tid = threadIdx.x;
    float z[2];
#pragma unroll
    for (int jj = 0; jj < 2; ++jj) {
        int c = tid + jj * 256;
        float s = V1[(long)b * H_ + c] + br[c];      // node0 row
#pragma unroll
        for (int kc = 0; kc < 13; ++kc)
            s += zparts[(long)kc * 16 * H_ + (long)b * H_ + c];
        z[jj] = s;
    }
    float s1 = z[0] + z[1];
    float s2 = z[0] * z[0] + z[1] * z[1];
#pragma unroll
    for (int off = 32; off > 0; off >>= 1) {
        s1 += __shfl_down(s1, off, 64);
        s2 += __shfl_down(s2, off, 64);
    }
    int wid = tid >> 6, lane = tid & 63;
    __syncthreads();
    if (lane == 0) { red[wid] = s1; red[4 + wid] = s2; }
    __syncthreads();
    float S1 = red[0] + red[1] + red[2] + red[3];
    float S2 = red[4] + red[5] + red[6] + red[7];
    float mu  = S1 * (1.0f / H_);
    float var = S2 * (1.0f / H_) - mu * mu;
    float rs  = rsqrtf(var + EPS);
#pragma unroll
    for (int jj = 0; jj < 2; ++jj) {
        int c = tid + jj * 256;
        zn[(long)b * H_ + c] = (z[jj] - mu) * rs * lng[c] + lnb[c];
    }
}

__global__ __launch_bounds__(256) void zlnred(
    const float* __restrict__ V1, const float* __restrict__ zparts,
    const float* __restrict__ br, const float* __restrict__ lng,
    const float* __restrict__ lnb, float* __restrict__ zn)
{
    __shared__ float red[8];
    zln_job(red, V1, zparts, br, lng, lnb, zn, blockIdx.x);
}

// hid = relu(b1 + sum_{kc<4} h1p[kc])
__device__ __forceinline__ void hred_job(const float* __restrict__ h1p,
                                         const float* __restrict__ b1,
                                         float* __restrict__ hid, int j)
{
    int b = j >> 2;
    int c = (j & 3) * 256 + threadIdx.x;
    float s = b1[c];
#pragma unroll
    for (int kc = 0; kc < 4; ++kc)
        s += h1p[(long)kc * 16 * F_ + (long)b * F_ + c];
    hid[(long)b * F_ + c] = fmaxf(s, 0.f);
}

__global__ __launch_bounds__(256) void hred(
    const float* __restrict__ h1p, const float* __restrict__ b1,
    float* __restrict__ hid)
{
    hred_job(h1p, b1, hid, blockIdx.x);
}

// out = b2 + sum_{kc<8} op[kc]
__device__ __forceinline__ void ored_job(const float* __restrict__ op,
                                         const float* __restrict__ b2,
                                         float* __restrict__ out, int j)
{
    int b = j >> 1;
    int c = (j & 1) * 256 + threadIdx.x;
    float s = b2[c];
#pragma unroll
    for (int kc = 0; kc < 8; ++kc)
        s += op[(long)kc * 16 * H_ + (long)b * H_ + c];
    out[(long)b * H_ + c] = s;
}

__global__ __launch_bounds__(256) void ored(
    const float* __restrict__ op, const float* __restrict__ b2,
    float* __restrict__ out)
{
    ored_job(op, b2, out, blockIdx.x);
}

// ---------------------------------------------------------------------------
// Persistent cooperative mega-kernel with two-level grid barrier.
// 512 blocks x 256 threads, 2 blocks/CU co-resident (LDS 26.6KB x2, VGPR 88).
// ---------------------------------------------------------------------------
__global__ __launch_bounds__(256, 2) void mega(
    const float* __restrict__ x, const float* __restrict__ We,
    const float* __restrict__ be, const float* __restrict__ Wb,
    const float* __restrict__ Amat, const float* __restrict__ Wr,
    const float* __restrict__ br, const float* __restrict__ lng,
    const float* __restrict__ lnb, const float* __restrict__ W1,
    const float* __restrict__ b1, const float* __restrict__ W2,
    const float* __restrict__ b2, float* __restrict__ out,
    float* __restrict__ ws, unsigned int* bar)
{
    __shared__ float sm[SMSZ];
    float* Wc  = ws;                         // 129 x 512
    float* V0  = Wc + 129 * H_;              // 2048 x 512
    float* V1  = V0 + 2048 * H_;             // 1024 x 512
    float* P2  = V1 + 1024 * H_;             // A^2
    float* P4  = P2 + H_ * H_;               // A^4
    float* P8  = P4 + H_ * H_;               // A^8
    float* P16 = P8 + H_ * H_;               // A^16
    float* P32 = P16 + H_ * H_;              // A^32
    float* P64 = P32 + H_ * H_;              // A^64
    float* P96 = P64 + H_ * H_;              // A^96
    float* zn  = P96 + H_ * H_;              // 16 x 512
    float* hid = zn + B_ * H_;               // 16 x 1024
    float* zp  = hid + B_ * F_;              // 13 x 16 x 512
    float* h1p = zp + 13 * B_ * H_;          // 4 x 16 x 1024
    float* op  = h1p + 4 * B_ * F_;          // 8 x 16 x 512

    const int bid = blockIdx.x;
    const int NB  = gridDim.x;

    // S0: Wc = [We;be]@Wb (40 jobs) || A^2 (128 jobs)
    for (int j = bid; j < 168; j += NB) {
        if (j < 40)
            gemm_tile(sm, We, be, Wb, nullptr, nullptr, Wc,
                      129, M_, M_, H_, H_, 0, 3, j & 7, j >> 3);
        else {
            int s = j - 40;
            gemm_tile(sm, Amat, nullptr, Amat, nullptr, nullptr, P2,
                      H_, H_, H_, H_, H_, 0, 0, s & 7, s >> 3);
        }
    }
    gbar(bar, NB);

    // S1: V0 = gather(x)@Wc + bc (512 jobs) || A^4 (128)
    for (int j = bid; j < 640; j += NB) {
        if (j < 512)
            gemm_tile(sm, x, nullptr, Wc, Wc + 128 * H_, nullptr, V0,
                      2048, L_, L_, H_, H_, 1, 1, j & 7, j >> 3);
        else {
            int s = j - 512;
            gemm_tile(sm, P2, nullptr, P2, nullptr, nullptr, P4,
                      H_, H_, H_, H_, H_, 0, 0, s & 7, s >> 3);
        }
    }
    gbar(bar, NB);

    // S2: tree L1: V1 = comb(V0, A), 1024 rows (256) || A^8 (128)
    for (int j = bid; j < 384; j += NB) {
        if (j < 256)
            gemm_tile(sm, V0, nullptr, Amat, nullptr, V0, V1,
                      1024, H_, H_, H_, H_, 0, 2, j & 7, j >> 3);
        else {
            int s = j - 256;
            gemm_tile(sm, P4, nullptr, P4, nullptr, nullptr, P8,
                      H_, H_, H_, H_, H_, 0, 0, s & 7, s >> 3);
        }
    }
    gbar(bar, NB);

    // S3: tree L2: V0 = comb(V1, A^2), 512 rows (128) || A^16 (128)
    for (int j = bid; j < 256; j += NB) {
        if (j < 128)
            gemm_tile(sm, V1, nullptr, P2, nullptr, V1, V0,
                      512, H_, H_, H_, H_, 0, 2, j & 7, j >> 3);
        else {
            int s = j - 128;
            gemm_tile(sm, P8, nullptr, P8, nullptr, nullptr, P16,
                      H_, H_, H_, H_, H_, 0, 0, s & 7, s >> 3);
        }
    }
    gbar(bar, NB);

    // S4: tree L3: V1 = comb(V0, A^4), 256 rows (64) || A^32 (128)
    for (int j = bid; j < 192; j += NB) {
        if (j < 64)
            gemm_tile(sm, V0, nullptr, P4, nullptr, V0, V1,
                      256, H_, H_, H_, H_, 0, 2, j & 7, j >> 3);
        else {
            int s = j - 64;
            gemm_tile(sm, P16, nullptr, P16, nullptr, nullptr, P32,
                      H_, H_, H_, H_, H_, 0, 0, s & 7, s >> 3);
        }
    }
    gbar(bar, NB);

    // S5: tree L4: V0 = comb(V1, A^8), 128 rows (32) || A^64 (128)
    for (int j = bid; j < 160; j += NB) {
        if (j < 32)
            gemm_tile(sm, V1, nullptr, P8, nullptr, V1, V0,
                      128, H_, H_, H_, H_, 0, 2, j & 7, j >> 3);
        else {
            int s = j - 32;
            gemm_tile(sm, P32, nullptr, P32, nullptr, nullptr, P64,
                      H_, H_, H_, H_, H_, 0, 0, s & 7, s >> 3);
        }
    }
    gbar(bar, NB);

    // S6: tree L5: V1 = comb(V0, A^16), 64 rows (16) || A^96 = A^32*A^64 (128)
    for (int j = bid; j < 144; j += NB) {
        if (j < 16)
            gemm_tile(sm, V0, nullptr, P16, nullptr, V0, V1,
                      64, H_, H_, H_, H_, 0, 2, j & 7, j >> 3);
        else {
            int s = j - 16;
            gemm_tile(sm, P32, nullptr, P64, nullptr, nullptr, P96,
                      H_, H_, H_, H_, H_, 0, 0, s & 7, s >> 3);
        }
    }
    gbar(bar, NB);

    // S7: z-partials (K=1664, 13 chunks x 8 col tiles = 104 jobs)
    for (int j = bid; j < 104; j += NB)
        tail_job<0>(sm, V1, x, P32, P64, P96, Wr, zp, 8, 128, j);
    gbar(bar, NB);

    // S7b: z reduce + LayerNorm -> zn (16 jobs)
    for (int j = bid; j < 16; j += NB)
        zln_job(sm, V1, zp, br, lng, lnb, zn, j);
    gbar(bar, NB);

    // S8: MLP1 partials (64 jobs)
    for (int j = bid; j < 64; j += NB)
        tail_job<1>(sm, zn, nullptr, nullptr, nullptr, nullptr, W1, h1p, 16, 128, j);
    gbar(bar, NB);

    // S8b: relu-reduce -> hid (64 jobs)
    for (int j = bid; j < 64; j += NB)
        hred_job(h1p, b1, hid, j);
    gbar(bar, NB);

    // S9: MLP2 partials (64 jobs)
    for (int j = bid; j < 64; j += NB)
        tail_job<2>(sm, hid, nullptr, nullptr, nullptr, nullptr, W2, op, 8, 128, j);
    gbar(bar, NB);

    // S9b: reduce -> out (32 jobs)
    for (int j = bid; j < 32; j += NB)
        ored_job(op, b2, out, j);
}

// ---------------------------------------------------------------------------
extern "C" void kernel_launch(void* const* d_in, const int* in_sizes, int n_in,
                              void* d_out, int out_size, void* d_ws, size_t ws_size,
                              hipStream_t stream) {
    const float* x    = (const float*)d_in[0];
    const float* We   = (const float*)d_in[1];
    const float* be   = (const float*)d_in[2];
    const float* Wb   = (const float*)d_in[3];
    const float* Amat = (const float*)d_in[4];
    const float* Wr   = (const float*)d_in[5];
    const float* br   = (const float*)d_in[6];
    const float* lng  = (const float*)d_in[7];
    const float* lnb  = (const float*)d_in[8];
    const float* W1   = (const float*)d_in[9];
    const float* b1   = (const float*)d_in[10];
    const float* W2   = (const float*)d_in[11];
    const float* b2   = (const float*)d_in[12];
    float* out = (float*)d_out;
    float* ws  = (float*)d_ws;

    // barrier state: last 1KB of workspace (far from the ~15MB of live data)
    unsigned int* bar =
        (unsigned int*)((char*)d_ws + ((ws_size - 1024) & ~(size_t)255));
    hipMemsetAsync(bar, 0, 1024, stream);

    // ---- cooperative mega-kernel path ----
    void* kargs[] = {
        (void*)&x,   (void*)&We,  (void*)&be,  (void*)&Wb,  (void*)&Amat,
        (void*)&Wr,  (void*)&br,  (void*)&lng, (void*)&lnb, (void*)&W1,
        (void*)&b1,  (void*)&W2,  (void*)&b2,  (void*)&out, (void*)&ws,
        (void*)&bar };

    hipError_t e = hipLaunchCooperativeKernel((const void*)mega, dim3(512),
                                              dim3(256), kargs, 0, stream);
    if (e != hipSuccess) {
        (void)hipGetLastError();
        e = hipLaunchCooperativeKernel((const void*)mega, dim3(256),
                                       dim3(256), kargs, 0, stream);
    }
    if (e == hipSuccess) return;
    (void)hipGetLastError();

    // ---- fallback: original 13-launch sequence ----
    float* Wc  = ws;
    float* V0  = Wc + 129 * H_;
    float* V1  = V0 + 2048 * H_;
    float* P2  = V1 + 1024 * H_;
    float* P4  = P2 + H_ * H_;
    float* P8  = P4 + H_ * H_;
    float* P16 = P8 + H_ * H_;
    float* P32 = P16 + H_ * H_;
    float* P64 = P32 + H_ * H_;
    float* P96 = P64 + H_ * H_;
    float* zn  = P96 + H_ * H_;
    float* hid = zn + B_ * H_;
    float* zp  = hid + B_ * F_;
    float* h1p = zp + 13 * B_ * H_;
    float* op  = h1p + 4 * B_ * F_;

    dual<<<168, 256, 0, stream>>>(We, be, Wb, nullptr, nullptr, Wc,
                                  129, M_, M_, H_, H_, 0, 3, 8, 40,
                                  Amat, Amat, P2);
    dual<<<640, 256, 0, stream>>>(x, nullptr, Wc, Wc + 128 * H_, nullptr, V0,
                                  2048, L_, L_, H_, H_, 1, 1, 8, 512,
                                  P2, P2, P4);
    dual<<<384, 256, 0, stream>>>(V0, nullptr, Amat, nullptr, V0, V1,
                                  1024, H_, H_, H_, H_, 0, 2, 8, 256,
                                  P4, P4, P8);
    dual<<<256, 256, 0, stream>>>(V1, nullptr, P2, nullptr, V1, V0,
                                  512, H_, H_, H_, H_, 0, 2, 8, 128,
                                  P8, P8, P16);
    dual<<<192, 256, 0, stream>>>(V0, nullptr, P4, nullptr, V0, V1,
                                  256, H_, H_, H_, H_, 0, 2, 8, 64,
                                  P16, P16, P32);
    dual<<<160, 256, 0, stream>>>(V1, nullptr, P8, nullptr, V1, V0,
                                  128, H_, H_, H_, H_, 0, 2, 8, 32,
                                  P32, P32, P64);
    dual<<<144, 256, 0, stream>>>(V0, nullptr, P16, nullptr, V0, V1,
                                  64, H_, H_, H_, H_, 0, 2, 8, 16,
                                  P32, P64, P96);
    tailgemm<0><<<104, 256, 0, stream>>>(V1, x, P32, P64, P96, Wr, zp, 8, 128);
    zlnred<<<16, 256, 0, stream>>>(V1, zp, br, lng, lnb, zn);
    tailgemm<1><<<64, 256, 0, stream>>>(zn, nullptr, nullptr, nullptr, nullptr,
                                        W1, h1p, 16, 128);
    hred<<<64, 256, 0, stream>>>(h1p, b1, hid);
    tailgemm<2><<<64, 256, 0, stream>>>(hid, nullptr, nullptr, nullptr, nullptr,
                                        W2, op, 8, 128);
    ored<<<32, 256, 0, stream>>>(op, b2, out);
}

// Round 4
// 1095.876 us; speedup vs baseline: 1.8207x; 1.6734x over previous
//
#include <hip/hip_runtime.h>

#define B_  16
#define T_  2048
#define L_  128
#define M_  256
#define H_  512
#define F_  1024
#define EPS 1e-5f

// LDS: As[64][36] + Bs[64][68] = 6656 floats = 26624 B  (2 blocks/CU)
#define LDA_S 36
#define LDB_S 68
#define SMSZ (64 * LDA_S + 64 * LDB_S)

#define NGRP 8

// ---------------------------------------------------------------------------
// Grid barrier with broadcast tree (all offsets 128B-separated):
//   bar[g*32]        g<8 : per-group arrival counters
//   bar[256]             : group-completion counter
//   bar[288]             : global generation word   (polled by 8 relays only)
//   bar[320 + g*32]  g<8 : per-group generation mirrors (polled by <=63 each)
// Round-2/3 post-mortem: 512 pollers on ONE agent-scope line (with per-poll
// ACQUIRE) serialize at the coherence point -> ~150us/barrier. This version:
// RELAXED polls, <=63 pollers/line, coarse s_sleep; one trailing threadfence
// supplies acquire. ph is a monotone phase number (bar memset to 0 each run).
// ---------------------------------------------------------------------------
__device__ __forceinline__ void gbar(unsigned int* bar, int nb,
                                     unsigned int ph) {
    __syncthreads();
    __threadfence();   // release: make this block's writes agent-visible
    if (threadIdx.x == 0) {
        const int g = blockIdx.x & (NGRP - 1);
        const unsigned int nInG = (unsigned int)nb / NGRP;   // nb % 8 == 0
        const unsigned int tgt = ph;
        unsigned int a = __hip_atomic_fetch_add(bar + g * 32, 1u,
                                                __ATOMIC_RELAXED,
                                                __HIP_MEMORY_SCOPE_AGENT);
        if (a == nInG - 1) {                       // group master
            __hip_atomic_store(bar + g * 32, 0u, __ATOMIC_RELAXED,
                               __HIP_MEMORY_SCOPE_AGENT);
            unsigned int d = __hip_atomic_fetch_add(bar + 256, 1u,
                                                    __ATOMIC_RELAXED,
                                                    __HIP_MEMORY_SCOPE_AGENT);
            if (d == NGRP - 1) {                   // global master
                __hip_atomic_store(bar + 256, 0u, __ATOMIC_RELAXED,
                                   __HIP_MEMORY_SCOPE_AGENT);
                __hip_atomic_store(bar + 288, tgt, __ATOMIC_RELEASE,
                                   __HIP_MEMORY_SCOPE_AGENT);
            } else {                               // relay: 7 pollers max
                while (__hip_atomic_load(bar + 288, __ATOMIC_RELAXED,
                                         __HIP_MEMORY_SCOPE_AGENT) < tgt)
                    __builtin_amdgcn_s_sleep(8);
            }
            __hip_atomic_store(bar + 320 + g * 32, tgt, __ATOMIC_RELAXED,
                               __HIP_MEMORY_SCOPE_AGENT);
        } else {                                   // member: <=63 pollers/line
            while (__hip_atomic_load(bar + 320 + g * 32, __ATOMIC_RELAXED,
                                     __HIP_MEMORY_SCOPE_AGENT) < tgt)
                __builtin_amdgcn_s_sleep(32);
        }
    }
    __syncthreads();
    __threadfence();   // acquire: invalidate before reading peers' data
}

// ---------------------------------------------------------------------------
// A-operand load with source remap.
// amode: 0 = row-major(lda); 1 = gather x[b=r&15][T-1-(r>>4)][:];
//        2 = tree (row -> vin[((r>>4)<<5)+16+(r&15)]);
//        3 = rows 0..M-2 from A, row M-1 from Alast
// ---------------------------------------------------------------------------
__device__ __forceinline__ float4 load_a4(const float* __restrict__ A,
                                          const float* __restrict__ Alast,
                                          int M, int lda, int amode,
                                          int gr, int gk) {
    float4 av = make_float4(0.f, 0.f, 0.f, 0.f);
    if (gr < M) {
        const float* p;
        if (amode == 1)
            p = A + (long)((gr & 15) * T_ + (T_ - 1 - (gr >> 4))) * L_ + gk;
        else if (amode == 2)
            p = A + (long)(((gr >> 4) << 5) + 16 + (gr & 15)) * lda + gk;
        else if (amode == 3 && gr == M - 1)
            p = Alast + gk;
        else
            p = A + (long)gr * lda + gk;
        av = *(const float4*)p;
    }
    return av;
}

// ---------------------------------------------------------------------------
// 32x64 tile GEMM, BK=64, TM=2 TN=4, 256 threads, reg-prefetch pipeline.
// ---------------------------------------------------------------------------
__device__ __forceinline__ void gemm_tile(
    float* sm,
    const float* __restrict__ A, const float* __restrict__ Alast,
    const float* __restrict__ Bm, const float* __restrict__ bias,
    const float* __restrict__ Add, float* __restrict__ C,
    int M, int K, int lda, int ldb, int ldc,
    int flags, int amode, int bx, int by)
{
    constexpr int BM = 32, BN = 64, BK = 64, TM = 2, TN = 4;
    float* As = sm;                    // [64][36] transposed A tile
    float* Bs = sm + BK * LDA_S;       // [64][68]
    const int tid = threadIdx.x;
    const int tx = tid & 15;           // BN/TN = 16
    const int ty = tid >> 4;           // 0..15
    const int row0 = by * BM, col0 = bx * BN;

    float4 pa[2], pb[4];
#pragma unroll
    for (int t = 0; t < 2; ++t) {
        int f = tid + t * 256;
        pa[t] = load_a4(A, Alast, M, lda, amode, row0 + (f >> 4), (f & 15) * 4);
    }
#pragma unroll
    for (int t = 0; t < 4; ++t) {
        int f = tid + t * 256;
        pb[t] = *(const float4*)(Bm + (long)(f >> 4) * ldb + col0 + (f & 15) * 4);
    }

    float acc[TM][TN] = {};

    for (int k0 = 0; k0 < K; k0 += BK) {
        __syncthreads();
#pragma unroll
        for (int t = 0; t < 2; ++t) {
            int f = tid + t * 256;
            int arow = f >> 4, kk = (f & 15) * 4;
            As[(kk + 0) * LDA_S + arow] = pa[t].x;
            As[(kk + 1) * LDA_S + arow] = pa[t].y;
            As[(kk + 2) * LDA_S + arow] = pa[t].z;
            As[(kk + 3) * LDA_S + arow] = pa[t].w;
        }
#pragma unroll
        for (int t = 0; t < 4; ++t) {
            int f = tid + t * 256;
            *(float4*)&Bs[(f >> 4) * LDB_S + (f & 15) * 4] = pb[t];
        }
        __syncthreads();
        int kn = k0 + BK;
        if (kn < K) {
#pragma unroll
            for (int t = 0; t < 2; ++t) {
                int f = tid + t * 256;
                pa[t] = load_a4(A, Alast, M, lda, amode, row0 + (f >> 4), kn + (f & 15) * 4);
            }
#pragma unroll
            for (int t = 0; t < 4; ++t) {
                int f = tid + t * 256;
                pb[t] = *(const float4*)(Bm + (long)(kn + (f >> 4)) * ldb + col0 + (f & 15) * 4);
            }
        }
#pragma unroll
        for (int kk = 0; kk < BK; ++kk) {
            float ra[TM], rb[TN];
#pragma unroll
            for (int i = 0; i < TM; ++i) ra[i] = As[kk * LDA_S + ty * TM + i];
#pragma unroll
            for (int j = 0; j < TN; ++j) rb[j] = Bs[kk * LDB_S + tx * TN + j];
#pragma unroll
            for (int i = 0; i < TM; ++i)
#pragma unroll
                for (int j = 0; j < TN; ++j)
                    acc[i][j] = fmaf(ra[i], rb[j], acc[i][j]);
        }
    }

#pragma unroll
    for (int i = 0; i < TM; ++i) {
        int r = row0 + ty * TM + i;
        if (r >= M) continue;
#pragma unroll
        for (int j = 0; j < TN; ++j) {
            int c = col0 + tx * TN + j;
            float v = acc[i][j];
            if (flags & 1) v += bias[c];
            if (amode == 2) v += Add[(long)(((r >> 4) << 5) + (r & 15)) * ldc + c];
            C[(long)r * ldc + c] = v;
        }
    }
}

// Dual-job kernel (FALLBACK path).
__global__ __launch_bounds__(256) void dual(
    const float* A, const float* Alast, const float* Bm, const float* bias,
    const float* Add, float* C, int M, int K, int lda, int ldb, int ldc,
    int flags, int amode, int nbxA, int nA,
    const float* SqL, const float* SqR, float* SqOut)
{
    __shared__ float sm[SMSZ];
    int j = blockIdx.x;
    if (j < nA)
        gemm_tile(sm, A, Alast, Bm, bias, Add, C, M, K, lda, ldb, ldc,
                  flags, amode, j % nbxA, j / nbxA);
    else {
        int s = j - nA;
        gemm_tile(sm, SqL, nullptr, SqR, nullptr, nullptr, SqOut,
                  H_, H_, H_, H_, H_, 0, 0, s % 8, s / 8);
    }
}

// ---------------------------------------------------------------------------
// Tail split-K GEMM (FALLBACK path only).
// ---------------------------------------------------------------------------
#define TLDA 20
#define TLDB 68
#define TSM (64 * TLDA + 64 * TLDB)

template <int MODE>
__device__ __forceinline__ float4 tail_a4(const float* __restrict__ Asrc,
                                          const float* __restrict__ x,
                                          int b, int gk) {
    if (MODE == 0) {
        int seg = gk >> 9;
        if (seg < 3)
            return *(const float4*)(Asrc + (long)((seg + 1) * 16 + b) * H_ + (gk & 511));
        return *(const float4*)(x + ((long)b * T_ + (T_ - 1)) * L_ + (gk - 1536));
    } else if (MODE == 1) {
        return *(const float4*)(Asrc + (long)b * H_ + gk);
    } else {
        return *(const float4*)(Asrc + (long)b * F_ + gk);
    }
}

template <int MODE>
__device__ __forceinline__ float4 tail_b4(const float* __restrict__ P32,
                                          const float* __restrict__ P64,
                                          const float* __restrict__ P96,
                                          const float* __restrict__ WrB,
                                          int kr, int c) {
    if (MODE == 0) {
        const float* p;
        if (kr < 512)       p = P32 + (long)kr * H_;
        else if (kr < 1024) p = P64 + (long)(kr - 512) * H_;
        else if (kr < 1536) p = P96 + (long)(kr - 1024) * H_;
        else                p = WrB + (long)(kr - 1536) * H_;
        return *(const float4*)(p + c);
    } else if (MODE == 1) {
        return *(const float4*)(WrB + (long)kr * F_ + c);
    } else {
        return *(const float4*)(WrB + (long)kr * H_ + c);
    }
}

template <int MODE>
__device__ __forceinline__ void tail_job(
    float* sm,
    const float* __restrict__ Asrc, const float* __restrict__ x,
    const float* __restrict__ P32, const float* __restrict__ P64,
    const float* __restrict__ P96, const float* __restrict__ WrB,
    float* __restrict__ parts, int nbx, int kLen, int jb)
{
    constexpr int LDC = (MODE == 1) ? F_ : H_;
    float* As = sm;
    float* Bs = sm + 64 * TLDA;
    const int tid = threadIdx.x;
    const int tx = tid & 15, ty = tid >> 4;
    const int kc = jb / nbx;
    const int col0 = (jb % nbx) * 64;
    const int kOff = kc * kLen;

    float4 pa, pb[4];
    {
        int gk = kOff + (tid & 15) * 4;
        pa = tail_a4<MODE>(Asrc, x, tid >> 4, gk);
#pragma unroll
        for (int t = 0; t < 4; ++t) {
            int f = tid + t * 256;
            pb[t] = tail_b4<MODE>(P32, P64, P96, WrB, kOff + (f >> 4), col0 + (f & 15) * 4);
        }
    }

    float acc[4] = {};
    for (int k0 = kOff; k0 < kOff + kLen; k0 += 64) {
        __syncthreads();
        {
            int arow = tid >> 4, kk = (tid & 15) * 4;
            As[(kk + 0) * TLDA + arow] = pa.x;
            As[(kk + 1) * TLDA + arow] = pa.y;
            As[(kk + 2) * TLDA + arow] = pa.z;
            As[(kk + 3) * TLDA + arow] = pa.w;
        }
#pragma unroll
        for (int t = 0; t < 4; ++t) {
            int f = tid + t * 256;
            *(float4*)&Bs[(f >> 4) * TLDB + (f & 15) * 4] = pb[t];
        }
        __syncthreads();
        int kn = k0 + 64;
        if (kn < kOff + kLen) {
            pa = tail_a4<MODE>(Asrc, x, tid >> 4, kn + (tid & 15) * 4);
#pragma unroll
            for (int t = 0; t < 4; ++t) {
                int f = tid + t * 256;
                pb[t] = tail_b4<MODE>(P32, P64, P96, WrB, kn + (f >> 4), col0 + (f & 15) * 4);
            }
        }
#pragma unroll
        for (int kk = 0; kk < 64; ++kk) {
            float ra = As[kk * TLDA + ty];
            float4 rb = *(float4*)&Bs[kk * TLDB + tx * 4];
            acc[0] = fmaf(ra, rb.x, acc[0]);
            acc[1] = fmaf(ra, rb.y, acc[1]);
            acc[2] = fmaf(ra, rb.z, acc[2]);
            acc[3] = fmaf(ra, rb.w, acc[3]);
        }
    }

    float* dst = parts + (long)kc * 16 * LDC + (long)ty * LDC + col0 + tx * 4;
    *(float4*)dst = make_float4(acc[0], acc[1], acc[2], acc[3]);
}

template <int MODE>
__global__ __launch_bounds__(256) void tailgemm(
    const float* __restrict__ Asrc, const float* __restrict__ x,
    const float* __restrict__ P32, const float* __restrict__ P64,
    const float* __restrict__ P96, const float* __restrict__ WrB,
    float* __restrict__ parts, int nbx, int kLen)
{
    __shared__ float sm[TSM];
    tail_job<MODE>(sm, Asrc, x, P32, P64, P96, WrB, parts, nbx, kLen, blockIdx.x);
}

// ---------------------------------------------------------------------------
// MEGA-path fused tail stages.
// ---------------------------------------------------------------------------

// Fused z-GEMM + LayerNorm, one job per batch row b (16 jobs).
// z[b][c] = V1node0[b][c] + br[c] + sum_k a[k]*Bk[k][c], K=1664 staged in LDS.
__device__ __forceinline__ void zfused_job(
    float* sm,
    const float* __restrict__ V1, const float* __restrict__ x,
    const float* __restrict__ P32, const float* __restrict__ P64,
    const float* __restrict__ P96, const float* __restrict__ Wr,
    const float* __restrict__ br, const float* __restrict__ lng,
    const float* __restrict__ lnb, float* __restrict__ zn, int b)
{
    const int tid = threadIdx.x;
    float* aS  = sm;              // 1664 floats (A row)
    float* red = sm + 1696;       // 8 floats
    for (int k = tid; k < 1664; k += 256) {
        int seg = k >> 9;
        float v;
        if (seg < 3) v = V1[(long)((seg + 1) * 16 + b) * H_ + (k & 511)];
        else         v = x[((long)b * T_ + (T_ - 1)) * L_ + (k - 1536)];
        aS[k] = v;
    }
    __syncthreads();

    const int c0 = tid * 2;
    float a0 = 0.f, a1 = 0.f;
#pragma unroll 4
    for (int k = 0; k < 512; ++k) {
        float a = aS[k];
        float2 bv = *(const float2*)(P32 + (long)k * H_ + c0);
        a0 = fmaf(a, bv.x, a0); a1 = fmaf(a, bv.y, a1);
    }
#pragma unroll 4
    for (int k = 0; k < 512; ++k) {
        float a = aS[512 + k];
        float2 bv = *(const float2*)(P64 + (long)k * H_ + c0);
        a0 = fmaf(a, bv.x, a0); a1 = fmaf(a, bv.y, a1);
    }
#pragma unroll 4
    for (int k = 0; k < 512; ++k) {
        float a = aS[1024 + k];
        float2 bv = *(const float2*)(P96 + (long)k * H_ + c0);
        a0 = fmaf(a, bv.x, a0); a1 = fmaf(a, bv.y, a1);
    }
#pragma unroll 4
    for (int k = 0; k < 128; ++k) {
        float a = aS[1536 + k];
        float2 bv = *(const float2*)(Wr + (long)k * H_ + c0);
        a0 = fmaf(a, bv.x, a0); a1 = fmaf(a, bv.y, a1);
    }
    float z0 = V1[(long)b * H_ + c0]     + br[c0]     + a0;
    float z1 = V1[(long)b * H_ + c0 + 1] + br[c0 + 1] + a1;

    float s1 = z0 + z1;
    float s2 = z0 * z0 + z1 * z1;
#pragma unroll
    for (int off = 32; off > 0; off >>= 1) {
        s1 += __shfl_down(s1, off, 64);
        s2 += __shfl_down(s2, off, 64);
    }
    int wid = tid >> 6, lane = tid & 63;
    __syncthreads();
    if (lane == 0) { red[wid] = s1; red[4 + wid] = s2; }
    __syncthreads();
    float S1 = red[0] + red[1] + red[2] + red[3];
    float S2 = red[4] + red[5] + red[6] + red[7];
    float mu  = S1 * (1.0f / H_);
    float var = S2 * (1.0f / H_) - mu * mu;
    float rs  = rsqrtf(var + EPS);
    zn[(long)b * H_ + c0]     = (z0 - mu) * rs * lng[c0]     + lnb[c0];
    zn[(long)b * H_ + c0 + 1] = (z1 - mu) * rs * lng[c0 + 1] + lnb[c0 + 1];
}

// Fused full-K MLP tile: MODE 1 = zn@W1 + b1, relu -> hid (16 jobs, K=512)
//                        MODE 2 = hid@W2 + b2 -> out     (8 jobs,  K=1024)
template <int MODE>
__device__ __forceinline__ void mlp_job(
    float* sm, const float* __restrict__ Asrc, const float* __restrict__ Bsrc,
    const float* __restrict__ bias, float* __restrict__ dst, int jb)
{
    constexpr int KLEN = (MODE == 1) ? H_ : F_;   // A row stride == K
    constexpr int LDB  = (MODE == 1) ? F_ : H_;   // B/dst row stride
    float* As = sm;                    // [64][20]
    float* Bs = sm + 64 * TLDA;        // [64][68]
    const int tid = threadIdx.x;
    const int tx = tid & 15, ty = tid >> 4;
    const int col0 = jb * 64;

    float4 pa, pb[4];
    pa = *(const float4*)(Asrc + (long)(tid >> 4) * KLEN + (tid & 15) * 4);
#pragma unroll
    for (int t = 0; t < 4; ++t) {
        int f = tid + t * 256;
        pb[t] = *(const float4*)(Bsrc + (long)(f >> 4) * LDB + col0 + (f & 15) * 4);
    }

    float acc[4] = {};
    for (int k0 = 0; k0 < KLEN; k0 += 64) {
        __syncthreads();
        {
            int arow = tid >> 4, kk = (tid & 15) * 4;
            As[(kk + 0) * TLDA + arow] = pa.x;
            As[(kk + 1) * TLDA + arow] = pa.y;
            As[(kk + 2) * TLDA + arow] = pa.z;
            As[(kk + 3) * TLDA + arow] = pa.w;
        }
#pragma unroll
        for (int t = 0; t < 4; ++t) {
            int f = tid + t * 256;
            *(float4*)&Bs[(f >> 4) * TLDB + (f & 15) * 4] = pb[t];
        }
        __syncthreads();
        int kn = k0 + 64;
        if (kn < KLEN) {
            pa = *(const float4*)(Asrc + (long)(tid >> 4) * KLEN + kn + (tid & 15) * 4);
#pragma unroll
            for (int t = 0; t < 4; ++t) {
                int f = tid + t * 256;
                pb[t] = *(const float4*)(Bsrc + (long)(kn + (f >> 4)) * LDB + col0 + (f & 15) * 4);
            }
        }
#pragma unroll
        for (int kk = 0; kk < 64; ++kk) {
            float ra = As[kk * TLDA + ty];
            float4 rb = *(float4*)&Bs[kk * TLDB + tx * 4];
            acc[0] = fmaf(ra, rb.x, acc[0]);
            acc[1] = fmaf(ra, rb.y, acc[1]);
            acc[2] = fmaf(ra, rb.z, acc[2]);
            acc[3] = fmaf(ra, rb.w, acc[3]);
        }
    }

    int c = col0 + tx * 4;
    float4 v;
    v.x = acc[0] + bias[c + 0];
    v.y = acc[1] + bias[c + 1];
    v.z = acc[2] + bias[c + 2];
    v.w = acc[3] + bias[c + 3];
    if (MODE == 1) {
        v.x = fmaxf(v.x, 0.f); v.y = fmaxf(v.y, 0.f);
        v.z = fmaxf(v.z, 0.f); v.w = fmaxf(v.w, 0.f);
    }
    *(float4*)(dst + (long)ty * LDB + c) = v;
}

// FALLBACK-path reduce kernels.
__global__ __launch_bounds__(256) void zlnred(
    const float* __restrict__ V1, const float* __restrict__ zparts,
    const float* __restrict__ br, const float* __restrict__ lng,
    const float* __restrict__ lnb, float* __restrict__ zn)
{
    __shared__ float red[8];
    const int b = blockIdx.x, tid = threadIdx.x;
    float z[2];
#pragma unroll
    for (int jj = 0; jj < 2; ++jj) {
        int c = tid + jj * 256;
        float s = V1[(long)b * H_ + c] + br[c];
#pragma unroll
        for (int kc = 0; kc < 13; ++kc)
            s += zparts[(long)kc * 16 * H_ + (long)b * H_ + c];
        z[jj] = s;
    }
    float s1 = z[0] + z[1];
    float s2 = z[0] * z[0] + z[1] * z[1];
#pragma unroll
    for (int off = 32; off > 0; off >>= 1) {
        s1 += __shfl_down(s1, off, 64);
        s2 += __shfl_down(s2, off, 64);
    }
    int wid = tid >> 6, lane = tid & 63;
    if (lane == 0) { red[wid] = s1; red[4 + wid] = s2; }
    __syncthreads();
    float S1 = red[0] + red[1] + red[2] + red[3];
    float S2 = red[4] + red[5] + red[6] + red[7];
    float mu  = S1 * (1.0f / H_);
    float var = S2 * (1.0f / H_) - mu * mu;
    float rs  = rsqrtf(var + EPS);
#pragma unroll
    for (int jj = 0; jj < 2; ++jj) {
        int c = tid + jj * 256;
        zn[(long)b * H_ + c] = (z[jj] - mu) * rs * lng[c] + lnb[c];
    }
}

__global__ __launch_bounds__(256) void hred(
    const float* __restrict__ h1p, const float* __restrict__ b1,
    float* __restrict__ hid)
{
    int b = blockIdx.x >> 2;
    int c = (blockIdx.x & 3) * 256 + threadIdx.x;
    float s = b1[c];
#pragma unroll
    for (int kc = 0; kc < 4; ++kc)
        s += h1p[(long)kc * 16 * F_ + (long)b * F_ + c];
    hid[(long)b * F_ + c] = fmaxf(s, 0.f);
}

__global__ __launch_bounds__(256) void ored(
    const float* __restrict__ op, const float* __restrict__ b2,
    float* __restrict__ out)
{
    int b = blockIdx.x >> 1;
    int c = (blockIdx.x & 1) * 256 + threadIdx.x;
    float s = b2[c];
#pragma unroll
    for (int kc = 0; kc < 8; ++kc)
        s += op[(long)kc * 16 * H_ + (long)b * H_ + c];
    out[(long)b * H_ + c] = s;
}

// ---------------------------------------------------------------------------
// Persistent cooperative mega-kernel: 9 broadcast-tree barriers, fused tail.
// 512 blocks x 256 threads, 2 blocks/CU co-resident.
// ---------------------------------------------------------------------------
__global__ __launch_bounds__(256, 2) void mega(
    const float* __restrict__ x, const float* __restrict__ We,
    const float* __restrict__ be, const float* __restrict__ Wb,
    const float* __restrict__ Amat, const float* __restrict__ Wr,
    const float* __restrict__ br, const float* __restrict__ lng,
    const float* __restrict__ lnb, const float* __restrict__ W1,
    const float* __restrict__ b1, const float* __restrict__ W2,
    const float* __restrict__ b2, float* __restrict__ out,
    float* __restrict__ ws, unsigned int* bar)
{
    __shared__ float sm[SMSZ];
    float* Wc  = ws;                         // 129 x 512
    float* V0  = Wc + 129 * H_;              // 2048 x 512
    float* V1  = V0 + 2048 * H_;             // 1024 x 512
    float* P2  = V1 + 1024 * H_;             // A^2
    float* P4  = P2 + H_ * H_;               // A^4
    float* P8  = P4 + H_ * H_;               // A^8
    float* P16 = P8 + H_ * H_;               // A^16
    float* P32 = P16 + H_ * H_;              // A^32
    float* P64 = P32 + H_ * H_;              // A^64
    float* P96 = P64 + H_ * H_;              // A^96
    float* zn  = P96 + H_ * H_;              // 16 x 512
    float* hid = zn + B_ * H_;               // 16 x 1024

    const int bid = blockIdx.x;
    const int NB  = gridDim.x;

    // S0: Wc = [We;be]@Wb (40 jobs) || A^2 (128 jobs)
    for (int j = bid; j < 168; j += NB) {
        if (j < 40)
            gemm_tile(sm, We, be, Wb, nullptr, nullptr, Wc,
                      129, M_, M_, H_, H_, 0, 3, j & 7, j >> 3);
        else {
            int s = j - 40;
            gemm_tile(sm, Amat, nullptr, Amat, nullptr, nullptr, P2,
                      H_, H_, H_, H_, H_, 0, 0, s & 7, s >> 3);
        }
    }
    gbar(bar, NB, 1);

    // S1: V0 = gather(x)@Wc + bc (512 jobs) || A^4 (128)
    for (int j = bid; j < 640; j += NB) {
        if (j < 512)
            gemm_tile(sm, x, nullptr, Wc, Wc + 128 * H_, nullptr, V0,
                      2048, L_, L_, H_, H_, 1, 1, j & 7, j >> 3);
        else {
            int s = j - 512;
            gemm_tile(sm, P2, nullptr, P2, nullptr, nullptr, P4,
                      H_, H_, H_, H_, H_, 0, 0, s & 7, s >> 3);
        }
    }
    gbar(bar, NB, 2);

    // S2: tree L1: V1 = comb(V0, A), 1024 rows (256) || A^8 (128)
    for (int j = bid; j < 384; j += NB) {
        if (j < 256)
            gemm_tile(sm, V0, nullptr, Amat, nullptr, V0, V1,
                      1024, H_, H_, H_, H_, 0, 2, j & 7, j >> 3);
        else {
            int s = j - 256;
            gemm_tile(sm, P4, nullptr, P4, nullptr, nullptr, P8,
                      H_, H_, H_, H_, H_, 0, 0, s & 7, s >> 3);
        }
    }
    gbar(bar, NB, 3);

    // S3: tree L2: V0 = comb(V1, A^2), 512 rows (128) || A^16 (128)
    for (int j = bid; j < 256; j += NB) {
        if (j < 128)
            gemm_tile(sm, V1, nullptr, P2, nullptr, V1, V0,
                      512, H_, H_, H_, H_, 0, 2, j & 7, j >> 3);
        else {
            int s = j - 128;
            gemm_tile(sm, P8, nullptr, P8, nullptr, nullptr, P16,
                      H_, H_, H_, H_, H_, 0, 0, s & 7, s >> 3);
        }
    }
    gbar(bar, NB, 4);

    // S4: tree L3: V1 = comb(V0, A^4), 256 rows (64) || A^32 (128)
    for (int j = bid; j < 192; j += NB) {
        if (j < 64)
            gemm_tile(sm, V0, nullptr, P4, nullptr, V0, V1,
                      256, H_, H_, H_, H_, 0, 2, j & 7, j >> 3);
        else {
            int s = j - 64;
            gemm_tile(sm, P16, nullptr, P16, nullptr, nullptr, P32,
                      H_, H_, H_, H_, H_, 0, 0, s & 7, s >> 3);
        }
    }
    gbar(bar, NB, 5);

    // S5: tree L4: V0 = comb(V1, A^8), 128 rows (32) || A^64 (128)
    for (int j = bid; j < 160; j += NB) {
        if (j < 32)
            gemm_tile(sm, V1, nullptr, P8, nullptr, V1, V0,
                      128, H_, H_, H_, H_, 0, 2, j & 7, j >> 3);
        else {
            int s = j - 32;
            gemm_tile(sm, P32, nullptr, P32, nullptr, nullptr, P64,
                      H_, H_, H_, H_, H_, 0, 0, s & 7, s >> 3);
        }
    }
    gbar(bar, NB, 6);

    // S6: tree L5: V1 = comb(V0, A^16), 64 rows (16) || A^96 = A^32*A^64 (128)
    for (int j = bid; j < 144; j += NB) {
        if (j < 16)
            gemm_tile(sm, V0, nullptr, P16, nullptr, V0, V1,
                      64, H_, H_, H_, H_, 0, 2, j & 7, j >> 3);
        else {
            int s = j - 16;
            gemm_tile(sm, P32, nullptr, P64, nullptr, nullptr, P96,
                      H_, H_, H_, H_, H_, 0, 0, s & 7, s >> 3);
        }
    }
    gbar(bar, NB, 7);

    // S7: fused z-GEMM + LayerNorm -> zn (16 jobs, one per batch row)
    for (int j = bid; j < 16; j += NB)
        zfused_job(sm, V1, x, P32, P64, P96, Wr, br, lng, lnb, zn, j);
    gbar(bar, NB, 8);

    // S8: fused MLP1 + bias + relu -> hid (16 col-tile jobs, full K=512)
    for (int j = bid; j < 16; j += NB)
        mlp_job<1>(sm, zn, W1, b1, hid, j);
    gbar(bar, NB, 9);

    // S9: fused MLP2 + bias -> out (8 col-tile jobs, full K=1024)
    for (int j = bid; j < 8; j += NB)
        mlp_job<2>(sm, hid, W2, b2, out, j);
}

// ---------------------------------------------------------------------------
extern "C" void kernel_launch(void* const* d_in, const int* in_sizes, int n_in,
                              void* d_out, int out_size, void* d_ws, size_t ws_size,
                              hipStream_t stream) {
    const float* x    = (const float*)d_in[0];
    const float* We   = (const float*)d_in[1];
    const float* be   = (const float*)d_in[2];
    const float* Wb   = (const float*)d_in[3];
    const float* Amat = (const float*)d_in[4];
    const float* Wr   = (const float*)d_in[5];
    const float* br   = (const float*)d_in[6];
    const float* lng  = (const float*)d_in[7];
    const float* lnb  = (const float*)d_in[8];
    const float* W1   = (const float*)d_in[9];
    const float* b1   = (const float*)d_in[10];
    const float* W2   = (const float*)d_in[11];
    const float* b2   = (const float*)d_in[12];
    float* out = (float*)d_out;
    float* ws  = (float*)d_ws;

    // barrier state: last 4KB of workspace
    unsigned int* bar =
        (unsigned int*)((char*)d_ws + ((ws_size - 4096) & ~(size_t)255));
    hipMemsetAsync(bar, 0, 4096, stream);

    // ---- cooperative mega-kernel path ----
    void* kargs[] = {
        (void*)&x,   (void*)&We,  (void*)&be,  (void*)&Wb,  (void*)&Amat,
        (void*)&Wr,  (void*)&br,  (void*)&lng, (void*)&lnb, (void*)&W1,
        (void*)&b1,  (void*)&W2,  (void*)&b2,  (void*)&out, (void*)&ws,
        (void*)&bar };

    hipError_t e = hipLaunchCooperativeKernel((const void*)mega, dim3(512),
                                              dim3(256), kargs, 0, stream);
    if (e != hipSuccess) {
        (void)hipGetLastError();
        e = hipLaunchCooperativeKernel((const void*)mega, dim3(256),
                                       dim3(256), kargs, 0, stream);
    }
    if (e == hipSuccess) return;
    (void)hipGetLastError();

    // ---- fallback: original 13-launch sequence ----
    float* Wc  = ws;
    float* V0  = Wc + 129 * H_;
    float* V1  = V0 + 2048 * H_;
    float* P2  = V1 + 1024 * H_;
    float* P4  = P2 + H_ * H_;
    float* P8  = P4 + H_ * H_;
    float* P16 = P8 + H_ * H_;
    float* P32 = P16 + H_ * H_;
    float* P64 = P32 + H_ * H_;
    float* P96 = P64 + H_ * H_;
    float* zn  = P96 + H_ * H_;
    float* hid = zn + B_ * H_;
    float* zp  = hid + B_ * F_;
    float* h1p = zp + 13 * B_ * H_;
    float* op  = h1p + 4 * B_ * F_;

    dual<<<168, 256, 0, stream>>>(We, be, Wb, nullptr, nullptr, Wc,
                                  129, M_, M_, H_, H_, 0, 3, 8, 40,
                                  Amat, Amat, P2);
    dual<<<640, 256, 0, stream>>>(x, nullptr, Wc, Wc + 128 * H_, nullptr, V0,
                                  2048, L_, L_, H_, H_, 1, 1, 8, 512,
                                  P2, P2, P4);
    dual<<<384, 256, 0, stream>>>(V0, nullptr, Amat, nullptr, V0, V1,
                                  1024, H_, H_, H_, H_, 0, 2, 8, 256,
                                  P4, P4, P8);
    dual<<<256, 256, 0, stream>>>(V1, nullptr, P2, nullptr, V1, V0,
                                  512, H_, H_, H_, H_, 0, 2, 8, 128,
                                  P8, P8, P16);
    dual<<<192, 256, 0, stream>>>(V0, nullptr, P4, nullptr, V0, V1,
                                  256, H_, H_, H_, H_, 0, 2, 8, 64,
                                  P16, P16, P32);
    dual<<<160, 256, 0, stream>>>(V1, nullptr, P8, nullptr, V1, V0,
                                  128, H_, H_, H_, H_, 0, 2, 8, 32,
                                  P32, P32, P64);
    dual<<<144, 256, 0, stream>>>(V0, nullptr, P16, nullptr, V0, V1,
                                  64, H_, H_, H_, H_, 0, 2, 8, 16,
                                  P32, P64, P96);
    tailgemm<0><<<104, 256, 0, stream>>>(V1, x, P32, P64, P96, Wr, zp, 8, 128);
    zlnred<<<16, 256, 0, stream>>>(V1, zp, br, lng, lnb, zn);
    tailgemm<1><<<64, 256, 0, stream>>>(zn, nullptr, nullptr, nullptr, nullptr,
                                        W1, h1p, 16, 128);
    hred<<<64, 256, 0, stream>>>(h1p, b1, hid);
    tailgemm<2><<<64, 256, 0, stream>>>(hid, nullptr, nullptr, nullptr, nullptr,
                                        W2, op, 8, 128);
    ored<<<32, 256, 0, stream>>>(op, b2, out);
}

// Round 6
// 326.946 us; speedup vs baseline: 6.1028x; 3.3519x over previous
//
#include <hip/hip_runtime.h>

#define B_  16
#define T_  2048
#define L_  128
#define M_  256
#define H_  512
#define F_  1024
#define EPS 1e-5f

// LDS: As[64][36] + Bs[64][68] = 6656 floats = 26624 B  (2 blocks/CU)
#define LDA_S 36
#define LDB_S 68
#define SMSZ (64 * LDA_S + 64 * LDB_S)

// ---------------------------------------------------------------------------
// A-operand load with source remap.
// amode: 0 = row-major(lda); 1 = gather x[b=r&15][T-1-(r>>4)][:];
//        2 = tree (row -> vin[((r>>4)<<5)+16+(r&15)]);
//        3 = rows 0..M-2 from A, row M-1 from Alast
// ---------------------------------------------------------------------------
__device__ __forceinline__ float4 load_a4(const float* __restrict__ A,
                                          const float* __restrict__ Alast,
                                          int M, int lda, int amode,
                                          int gr, int gk) {
    float4 av = make_float4(0.f, 0.f, 0.f, 0.f);
    if (gr < M) {
        const float* p;
        if (amode == 1)
            p = A + (long)((gr & 15) * T_ + (T_ - 1 - (gr >> 4))) * L_ + gk;
        else if (amode == 2)
            p = A + (long)(((gr >> 4) << 5) + 16 + (gr & 15)) * lda + gk;
        else if (amode == 3 && gr == M - 1)
            p = Alast + gk;
        else
            p = A + (long)gr * lda + gk;
        av = *(const float4*)p;
    }
    return av;
}

// ---------------------------------------------------------------------------
// 32x64 tile GEMM, BK=64, TM=2 TN=4, 256 threads, reg-prefetch pipeline.
// flags: 1 = +bias[c].  amode==2 epilogue adds Add[((r>>4)<<5)+(r&15)].
// ---------------------------------------------------------------------------
__device__ __forceinline__ void gemm_tile(
    float* sm,
    const float* __restrict__ A, const float* __restrict__ Alast,
    const float* __restrict__ Bm, const float* __restrict__ bias,
    const float* __restrict__ Add, float* __restrict__ C,
    int M, int K, int lda, int ldb, int ldc,
    int flags, int amode, int bx, int by)
{
    constexpr int BM = 32, BN = 64, BK = 64, TM = 2, TN = 4;
    float* As = sm;                    // [64][36] transposed A tile
    float* Bs = sm + BK * LDA_S;       // [64][68]
    const int tid = threadIdx.x;
    const int tx = tid & 15;           // BN/TN = 16
    const int ty = tid >> 4;           // 0..15
    const int row0 = by * BM, col0 = bx * BN;

    float4 pa[2], pb[4];
#pragma unroll
    for (int t = 0; t < 2; ++t) {
        int f = tid + t * 256;
        pa[t] = load_a4(A, Alast, M, lda, amode, row0 + (f >> 4), (f & 15) * 4);
    }
#pragma unroll
    for (int t = 0; t < 4; ++t) {
        int f = tid + t * 256;
        pb[t] = *(const float4*)(Bm + (long)(f >> 4) * ldb + col0 + (f & 15) * 4);
    }

    float acc[TM][TN] = {};

    for (int k0 = 0; k0 < K; k0 += BK) {
        __syncthreads();               // prior compute done reading LDS
#pragma unroll
        for (int t = 0; t < 2; ++t) {
            int f = tid + t * 256;
            int arow = f >> 4, kk = (f & 15) * 4;
            As[(kk + 0) * LDA_S + arow] = pa[t].x;
            As[(kk + 1) * LDA_S + arow] = pa[t].y;
            As[(kk + 2) * LDA_S + arow] = pa[t].z;
            As[(kk + 3) * LDA_S + arow] = pa[t].w;
        }
#pragma unroll
        for (int t = 0; t < 4; ++t) {
            int f = tid + t * 256;
            *(float4*)&Bs[(f >> 4) * LDB_S + (f & 15) * 4] = pb[t];
        }
        __syncthreads();
        int kn = k0 + BK;
        if (kn < K) {                  // prefetch next tiles; in flight during FMAs
#pragma unroll
            for (int t = 0; t < 2; ++t) {
                int f = tid + t * 256;
                pa[t] = load_a4(A, Alast, M, lda, amode, row0 + (f >> 4), kn + (f & 15) * 4);
            }
#pragma unroll
            for (int t = 0; t < 4; ++t) {
                int f = tid + t * 256;
                pb[t] = *(const float4*)(Bm + (long)(kn + (f >> 4)) * ldb + col0 + (f & 15) * 4);
            }
        }
#pragma unroll
        for (int kk = 0; kk < BK; ++kk) {
            float ra[TM], rb[TN];
#pragma unroll
            for (int i = 0; i < TM; ++i) ra[i] = As[kk * LDA_S + ty * TM + i];
#pragma unroll
            for (int j = 0; j < TN; ++j) rb[j] = Bs[kk * LDB_S + tx * TN + j];
#pragma unroll
            for (int i = 0; i < TM; ++i)
#pragma unroll
                for (int j = 0; j < TN; ++j)
                    acc[i][j] = fmaf(ra[i], rb[j], acc[i][j]);
        }
    }

#pragma unroll
    for (int i = 0; i < TM; ++i) {
        int r = row0 + ty * TM + i;
        if (r >= M) continue;
#pragma unroll
        for (int j = 0; j < TN; ++j) {
            int c = col0 + tx * TN + j;
            float v = acc[i][j];
            if (flags & 1) v += bias[c];
            if (amode == 2) v += Add[(long)(((r >> 4) << 5) + (r & 15)) * ldc + c];
            C[(long)r * ldc + c] = v;
        }
    }
}

// Dual-job kernel: blocks [0,nA) run job A; blocks [nA, ...) compute
// SqOut = SqL @ SqR (512x512x512) for the A-power chain.
__global__ __launch_bounds__(256) void dual(
    const float* A, const float* Alast, const float* Bm, const float* bias,
    const float* Add, float* C, int M, int K, int lda, int ldb, int ldc,
    int flags, int amode, int nbxA, int nA,
    const float* SqL, const float* SqR, float* SqOut)
{
    __shared__ float sm[SMSZ];
    int j = blockIdx.x;
    if (j < nA)
        gemm_tile(sm, A, Alast, Bm, bias, Add, C, M, K, lda, ldb, ldc,
                  flags, amode, j % nbxA, j / nbxA);
    else {
        int s = j - nA;
        gemm_tile(sm, SqL, nullptr, SqR, nullptr, nullptr, SqOut,
                  H_, H_, H_, H_, H_, 0, 0, s % 8, s / 8);
    }
}

// ---------------------------------------------------------------------------
// z-partials split-K GEMM: BM=16, BN=64, BK=64, 256 threads.
// A = [V1nodes1..3 | x_last] (K=1664), B = [P32;P64;P96;Wr]
// Writes partials: zp[kc][16][H_], kc = blockIdx.x / 8.
// ---------------------------------------------------------------------------
#define TLDA 20
#define TLDB 68
#define TSM (64 * TLDA + 64 * TLDB)

__device__ __forceinline__ float4 z_a4(const float* __restrict__ V1,
                                       const float* __restrict__ x,
                                       int b, int gk) {
    int seg = gk >> 9;
    if (seg < 3)
        return *(const float4*)(V1 + (long)((seg + 1) * 16 + b) * H_ + (gk & 511));
    return *(const float4*)(x + ((long)b * T_ + (T_ - 1)) * L_ + (gk - 1536));
}

__device__ __forceinline__ float4 z_b4(const float* __restrict__ P32,
                                       const float* __restrict__ P64,
                                       const float* __restrict__ P96,
                                       const float* __restrict__ Wr,
                                       int kr, int c) {
    const float* p;
    if (kr < 512)       p = P32 + (long)kr * H_;
    else if (kr < 1024) p = P64 + (long)(kr - 512) * H_;
    else if (kr < 1536) p = P96 + (long)(kr - 1024) * H_;
    else                p = Wr + (long)(kr - 1536) * H_;
    return *(const float4*)(p + c);
}

__global__ __launch_bounds__(256) void zpart(
    const float* __restrict__ V1, const float* __restrict__ x,
    const float* __restrict__ P32, const float* __restrict__ P64,
    const float* __restrict__ P96, const float* __restrict__ Wr,
    float* __restrict__ zp)
{
    __shared__ float sm[TSM];
    float* As = sm;                    // [64][20] transposed (A[k][row])
    float* Bs = sm + 64 * TLDA;        // [64][68]
    const int tid = threadIdx.x;
    const int tx = tid & 15, ty = tid >> 4;      // ty = row 0..15
    const int kc = blockIdx.x >> 3;
    const int col0 = (blockIdx.x & 7) * 64;
    const int kOff = kc * 128;

    float4 pa, pb[4];
    pa = z_a4(V1, x, tid >> 4, kOff + (tid & 15) * 4);
#pragma unroll
    for (int t = 0; t < 4; ++t) {
        int f = tid + t * 256;
        pb[t] = z_b4(P32, P64, P96, Wr, kOff + (f >> 4), col0 + (f & 15) * 4);
    }

    float acc[4] = {};
    for (int k0 = kOff; k0 < kOff + 128; k0 += 64) {
        __syncthreads();
        {
            int arow = tid >> 4, kk = (tid & 15) * 4;
            As[(kk + 0) * TLDA + arow] = pa.x;
            As[(kk + 1) * TLDA + arow] = pa.y;
            As[(kk + 2) * TLDA + arow] = pa.z;
            As[(kk + 3) * TLDA + arow] = pa.w;
        }
#pragma unroll
        for (int t = 0; t < 4; ++t) {
            int f = tid + t * 256;
            *(float4*)&Bs[(f >> 4) * TLDB + (f & 15) * 4] = pb[t];
        }
        __syncthreads();
        int kn = k0 + 64;
        if (kn < kOff + 128) {
            pa = z_a4(V1, x, tid >> 4, kn + (tid & 15) * 4);
#pragma unroll
            for (int t = 0; t < 4; ++t) {
                int f = tid + t * 256;
                pb[t] = z_b4(P32, P64, P96, Wr, kn + (f >> 4), col0 + (f & 15) * 4);
            }
        }
#pragma unroll
        for (int kk = 0; kk < 64; ++kk) {
            float ra = As[kk * TLDA + ty];
            float4 rb = *(float4*)&Bs[kk * TLDB + tx * 4];
            acc[0] = fmaf(ra, rb.x, acc[0]);
            acc[1] = fmaf(ra, rb.y, acc[1]);
            acc[2] = fmaf(ra, rb.z, acc[2]);
            acc[3] = fmaf(ra, rb.w, acc[3]);
        }
    }

    float* dst = zp + (long)kc * 16 * H_ + (long)ty * H_ + col0 + tx * 4;
    *(float4*)dst = make_float4(acc[0], acc[1], acc[2], acc[3]);
}

// ---------------------------------------------------------------------------
// Fused: z = node0 + br + sum(zp); LayerNorm -> zn (kept in LDS);
// hid tile = relu(zn @ W1[:, col0:col0+64] + b1).  grid = 16 blocks.
// Thread layout phase 1: row r = tid>>4, 16 lanes/row, float4-coalesced.
// ---------------------------------------------------------------------------
__global__ __launch_bounds__(256) void mlp1z(
    const float* __restrict__ V1, const float* __restrict__ zp,
    const float* __restrict__ br, const float* __restrict__ lng,
    const float* __restrict__ lnb, const float* __restrict__ W1,
    const float* __restrict__ b1, float* __restrict__ hid)
{
    __shared__ float znL[16 * 512];        // 32 KB
    __shared__ float Bs[64 * TLDB];        // 17.4 KB
    const int tid = threadIdx.x;

    // ---- phase 1: z-reduce + LayerNorm -> znL ----
    {
        const int r = tid >> 4;            // row 0..15
        const int l = tid & 15;            // lane in row
        float4 zv[8];
        float s1 = 0.f, s2 = 0.f;
#pragma unroll
        for (int i = 0; i < 8; ++i) {
            int c = l * 4 + i * 64;
            float4 v = *(const float4*)(V1 + (long)r * H_ + c);   // node0
            float4 bb = *(const float4*)(br + c);
            v.x += bb.x; v.y += bb.y; v.z += bb.z; v.w += bb.w;
#pragma unroll
            for (int kc = 0; kc < 13; ++kc) {
                float4 p = *(const float4*)(zp + (long)kc * 16 * H_ + (long)r * H_ + c);
                v.x += p.x; v.y += p.y; v.z += p.z; v.w += p.w;
            }
            zv[i] = v;
            s1 += v.x + v.y + v.z + v.w;
            s2 += v.x * v.x + v.y * v.y + v.z * v.z + v.w * v.w;
        }
        // reduce across the 16 lanes of this row (lane-aligned subgroup)
#pragma unroll
        for (int off = 1; off < 16; off <<= 1) {
            s1 += __shfl_xor(s1, off, 64);
            s2 += __shfl_xor(s2, off, 64);
        }
        float mu  = s1 * (1.0f / H_);
        float var = s2 * (1.0f / H_) - mu * mu;
        float rs  = rsqrtf(var + EPS);
#pragma unroll
        for (int i = 0; i < 8; ++i) {
            int c = l * 4 + i * 64;
            float4 g  = *(const float4*)(lng + c);
            float4 bt = *(const float4*)(lnb + c);
            float4 v  = zv[i];
            v.x = (v.x - mu) * rs * g.x + bt.x;
            v.y = (v.y - mu) * rs * g.y + bt.y;
            v.z = (v.z - mu) * rs * g.z + bt.z;
            v.w = (v.w - mu) * rs * g.w + bt.w;
            *(float4*)&znL[r * 512 + c] = v;
        }
    }
    __syncthreads();

    // ---- phase 2: hid tile = relu(znL @ W1 + b1), K = 512 ----
    const int tx = tid & 15, ty = tid >> 4;
    const int col0 = blockIdx.x * 64;

    float4 pb[4];
#pragma unroll
    for (int t = 0; t < 4; ++t) {
        int f = tid + t * 256;
        pb[t] = *(const float4*)(W1 + (long)(f >> 4) * F_ + col0 + (f & 15) * 4);
    }
    float acc[4] = {};
    for (int k0 = 0; k0 < H_; k0 += 64) {
        __syncthreads();
#pragma unroll
        for (int t = 0; t < 4; ++t) {
            int f = tid + t * 256;
            *(float4*)&Bs[(f >> 4) * TLDB + (f & 15) * 4] = pb[t];
        }
        __syncthreads();
        int kn = k0 + 64;
        if (kn < H_) {
#pragma unroll
            for (int t = 0; t < 4; ++t) {
                int f = tid + t * 256;
                pb[t] = *(const float4*)(W1 + (long)(kn + (f >> 4)) * F_ + col0 + (f & 15) * 4);
            }
        }
#pragma unroll
        for (int kk = 0; kk < 64; ++kk) {
            float ra = znL[ty * 512 + k0 + kk];    // broadcast across tx lanes
            float4 rb = *(float4*)&Bs[kk * TLDB + tx * 4];
            acc[0] = fmaf(ra, rb.x, acc[0]);
            acc[1] = fmaf(ra, rb.y, acc[1]);
            acc[2] = fmaf(ra, rb.z, acc[2]);
            acc[3] = fmaf(ra, rb.w, acc[3]);
        }
    }
    int c = col0 + tx * 4;
    float4 v;
    v.x = fmaxf(acc[0] + b1[c + 0], 0.f);
    v.y = fmaxf(acc[1] + b1[c + 1], 0.f);
    v.z = fmaxf(acc[2] + b1[c + 2], 0.f);
    v.w = fmaxf(acc[3] + b1[c + 3], 0.f);
    *(float4*)(hid + (long)ty * F_ + c) = v;
}

// ---------------------------------------------------------------------------
// Fused full-K MLP2: out tile = hid @ W2[:, col0:col0+64] + b2.  grid = 8.
// K = 1024, A rows (16) staged transposed in LDS per K-step.
// ---------------------------------------------------------------------------
__global__ __launch_bounds__(256) void mlp2k(
    const float* __restrict__ hid, const float* __restrict__ W2,
    const float* __restrict__ b2, float* __restrict__ out)
{
    __shared__ float sm[TSM];
    float* As = sm;                    // [64][20]
    float* Bs = sm + 64 * TLDA;        // [64][68]
    const int tid = threadIdx.x;
    const int tx = tid & 15, ty = tid >> 4;
    const int col0 = blockIdx.x * 64;

    float4 pa, pb[4];
    pa = *(const float4*)(hid + (long)(tid >> 4) * F_ + (tid & 15) * 4);
#pragma unroll
    for (int t = 0; t < 4; ++t) {
        int f = tid + t * 256;
        pb[t] = *(const float4*)(W2 + (long)(f >> 4) * H_ + col0 + (f & 15) * 4);
    }

    float acc[4] = {};
    for (int k0 = 0; k0 < F_; k0 += 64) {
        __syncthreads();
        {
            int arow = tid >> 4, kk = (tid & 15) * 4;
            As[(kk + 0) * TLDA + arow] = pa.x;
            As[(kk + 1) * TLDA + arow] = pa.y;
            As[(kk + 2) * TLDA + arow] = pa.z;
            As[(kk + 3) * TLDA + arow] = pa.w;
        }
#pragma unroll
        for (int t = 0; t < 4; ++t) {
            int f = tid + t * 256;
            *(float4*)&Bs[(f >> 4) * TLDB + (f & 15) * 4] = pb[t];
        }
        __syncthreads();
        int kn = k0 + 64;
        if (kn < F_) {
            pa = *(const float4*)(hid + (long)(tid >> 4) * F_ + kn + (tid & 15) * 4);
#pragma unroll
            for (int t = 0; t < 4; ++t) {
                int f = tid + t * 256;
                pb[t] = *(const float4*)(W2 + (long)(kn + (f >> 4)) * H_ + col0 + (f & 15) * 4);
            }
        }
#pragma unroll
        for (int kk = 0; kk < 64; ++kk) {
            float ra = As[kk * TLDA + ty];
            float4 rb = *(float4*)&Bs[kk * TLDB + tx * 4];
            acc[0] = fmaf(ra, rb.x, acc[0]);
            acc[1] = fmaf(ra, rb.y, acc[1]);
            acc[2] = fmaf(ra, rb.z, acc[2]);
            acc[3] = fmaf(ra, rb.w, acc[3]);
        }
    }

    int c = col0 + tx * 4;
    float4 v;
    v.x = acc[0] + b2[c + 0];
    v.y = acc[1] + b2[c + 1];
    v.z = acc[2] + b2[c + 2];
    v.w = acc[3] + b2[c + 3];
    *(float4*)(out + (long)ty * H_ + c) = v;
}

// ---------------------------------------------------------------------------
// 10-launch pipeline (structural floor for this decomposition: the A-power
// chain A^2..A^96 is depth-7 by the doubling bound; tree stages co-scheduled).
// In-kernel grid barriers were measured at ~70-160us each on this 8-XCD chip
// (rounds 1-4) vs ~15us per kernel boundary -> multi-launch wins.
// ---------------------------------------------------------------------------
extern "C" void kernel_launch(void* const* d_in, const int* in_sizes, int n_in,
                              void* d_out, int out_size, void* d_ws, size_t ws_size,
                              hipStream_t stream) {
    const float* x    = (const float*)d_in[0];
    const float* We   = (const float*)d_in[1];
    const float* be   = (const float*)d_in[2];
    const float* Wb   = (const float*)d_in[3];
    const float* Amat = (const float*)d_in[4];
    const float* Wr   = (const float*)d_in[5];
    const float* br   = (const float*)d_in[6];
    const float* lng  = (const float*)d_in[7];
    const float* lnb  = (const float*)d_in[8];
    const float* W1   = (const float*)d_in[9];
    const float* b1   = (const float*)d_in[10];
    const float* W2   = (const float*)d_in[11];
    const float* b2   = (const float*)d_in[12];
    float* out = (float*)d_out;

    float* ws  = (float*)d_ws;
    float* Wc  = ws;                         // 129 x 512
    float* V0  = Wc + 129 * H_;              // 2048 x 512
    float* V1  = V0 + 2048 * H_;             // 1024 x 512
    float* P2  = V1 + 1024 * H_;             // A^2
    float* P4  = P2 + H_ * H_;               // A^4
    float* P8  = P4 + H_ * H_;               // A^8
    float* P16 = P8 + H_ * H_;               // A^16
    float* P32 = P16 + H_ * H_;              // A^32
    float* P64 = P32 + H_ * H_;              // A^64
    float* P96 = P64 + H_ * H_;              // A^96
    float* hid = P96 + H_ * H_;              // 16 x 1024
    float* zp  = hid + B_ * F_;              // 13 x 16 x 512

    // K0: Wc = [We;be]@Wb (129x512,K=256) [40] || A^2 [128]
    dual<<<168, 256, 0, stream>>>(We, be, Wb, nullptr, nullptr, Wc,
                                  129, M_, M_, H_, H_, 0, 3, 8, 40,
                                  Amat, Amat, P2);
    // K1: V0 = gather(x)@Wc + bc (2048x512,K=128) [512] || A^4 [128]
    dual<<<640, 256, 0, stream>>>(x, nullptr, Wc, Wc + 128 * H_, nullptr, V0,
                                  2048, L_, L_, H_, H_, 1, 1, 8, 512,
                                  P2, P2, P4);
    // K2 (l1): V1 = comb(V0, A), 1024 rows [256] || A^8 [128]
    dual<<<384, 256, 0, stream>>>(V0, nullptr, Amat, nullptr, V0, V1,
                                  1024, H_, H_, H_, H_, 0, 2, 8, 256,
                                  P4, P4, P8);
    // K3 (l2): V0 = comb(V1, A^2), 512 rows [128] || A^16 [128]
    dual<<<256, 256, 0, stream>>>(V1, nullptr, P2, nullptr, V1, V0,
                                  512, H_, H_, H_, H_, 0, 2, 8, 128,
                                  P8, P8, P16);
    // K4 (l3): V1 = comb(V0, A^4), 256 rows [64] || A^32 [128]
    dual<<<192, 256, 0, stream>>>(V0, nullptr, P4, nullptr, V0, V1,
                                  256, H_, H_, H_, H_, 0, 2, 8, 64,
                                  P16, P16, P32);
    // K5 (l4): V0 = comb(V1, A^8), 128 rows [32] || A^64 [128]
    dual<<<160, 256, 0, stream>>>(V1, nullptr, P8, nullptr, V1, V0,
                                  128, H_, H_, H_, H_, 0, 2, 8, 32,
                                  P32, P32, P64);
    // K6 (l5): V1 = comb(V0, A^16), 64 rows (4 nodes) [16] || A^96 [128]
    dual<<<144, 256, 0, stream>>>(V0, nullptr, P16, nullptr, V0, V1,
                                  64, H_, H_, H_, H_, 0, 2, 8, 16,
                                  P32, P64, P96);
    // K7: z-partials (K=1664, 13 chunks x 8 col tiles)
    zpart<<<104, 256, 0, stream>>>(V1, x, P32, P64, P96, Wr, zp);
    // K8: fused z-reduce + LayerNorm (zn in LDS) + MLP1 + relu -> hid
    mlp1z<<<16, 256, 0, stream>>>(V1, zp, br, lng, lnb, W1, b1, hid);
    // K9: fused full-K MLP2 + bias -> out
    mlp2k<<<8, 256, 0, stream>>>(hid, W2, b2, out);
}

// Round 7
// 291.467 us; speedup vs baseline: 6.8456x; 1.1217x over previous
//
#include <hip/hip_runtime.h>

#define B_  16
#define T_  2048
#define L_  128
#define M_  256
#define H_  512
#define F_  1024
#define EPS 1e-5f

// LDS: As[64][36] + Bs[64][68] = 6656 floats = 26624 B  (2 blocks/CU)
#define LDA_S 36
#define LDB_S 68
#define SMSZ (64 * LDA_S + 64 * LDB_S)

// ---------------------------------------------------------------------------
// A-operand load with source remap.
// amode: 0 = row-major(lda); 1 = gather x[b=r&15][T-1-(r>>4)][:];
//        2 = tree (row -> vin[((r>>4)<<5)+16+(r&15)]);
//        3 = rows 0..M-2 from A, row M-1 from Alast
// ---------------------------------------------------------------------------
__device__ __forceinline__ float4 load_a4(const float* __restrict__ A,
                                          const float* __restrict__ Alast,
                                          int M, int lda, int amode,
                                          int gr, int gk) {
    float4 av = make_float4(0.f, 0.f, 0.f, 0.f);
    if (gr < M) {
        const float* p;
        if (amode == 1)
            p = A + (long)((gr & 15) * T_ + (T_ - 1 - (gr >> 4))) * L_ + gk;
        else if (amode == 2)
            p = A + (long)(((gr >> 4) << 5) + 16 + (gr & 15)) * lda + gk;
        else if (amode == 3 && gr == M - 1)
            p = Alast + gk;
        else
            p = A + (long)gr * lda + gk;
        av = *(const float4*)p;
    }
    return av;
}

// ---------------------------------------------------------------------------
// 32x64 tile GEMM, BK=64, TM=2 TN=4, 256 threads, reg-prefetch pipeline.
// flags: 1 = +bias[c].  amode==2 epilogue adds Add[((r>>4)<<5)+(r&15)].
// ---------------------------------------------------------------------------
__device__ __forceinline__ void gemm_tile(
    float* sm,
    const float* __restrict__ A, const float* __restrict__ Alast,
    const float* __restrict__ Bm, const float* __restrict__ bias,
    const float* __restrict__ Add, float* __restrict__ C,
    int M, int K, int lda, int ldb, int ldc,
    int flags, int amode, int bx, int by)
{
    constexpr int BM = 32, BN = 64, BK = 64, TM = 2, TN = 4;
    float* As = sm;                    // [64][36] transposed A tile
    float* Bs = sm + BK * LDA_S;       // [64][68]
    const int tid = threadIdx.x;
    const int tx = tid & 15;           // BN/TN = 16
    const int ty = tid >> 4;           // 0..15
    const int row0 = by * BM, col0 = bx * BN;

    float4 pa[2], pb[4];
#pragma unroll
    for (int t = 0; t < 2; ++t) {
        int f = tid + t * 256;
        pa[t] = load_a4(A, Alast, M, lda, amode, row0 + (f >> 4), (f & 15) * 4);
    }
#pragma unroll
    for (int t = 0; t < 4; ++t) {
        int f = tid + t * 256;
        pb[t] = *(const float4*)(Bm + (long)(f >> 4) * ldb + col0 + (f & 15) * 4);
    }

    float acc[TM][TN] = {};

    for (int k0 = 0; k0 < K; k0 += BK) {
        __syncthreads();               // prior compute done reading LDS
#pragma unroll
        for (int t = 0; t < 2; ++t) {
            int f = tid + t * 256;
            int arow = f >> 4, kk = (f & 15) * 4;
            As[(kk + 0) * LDA_S + arow] = pa[t].x;
            As[(kk + 1) * LDA_S + arow] = pa[t].y;
            As[(kk + 2) * LDA_S + arow] = pa[t].z;
            As[(kk + 3) * LDA_S + arow] = pa[t].w;
        }
#pragma unroll
        for (int t = 0; t < 4; ++t) {
            int f = tid + t * 256;
            *(float4*)&Bs[(f >> 4) * LDB_S + (f & 15) * 4] = pb[t];
        }
        __syncthreads();
        int kn = k0 + BK;
        if (kn < K) {                  // prefetch next tiles; in flight during FMAs
#pragma unroll
            for (int t = 0; t < 2; ++t) {
                int f = tid + t * 256;
                pa[t] = load_a4(A, Alast, M, lda, amode, row0 + (f >> 4), kn + (f & 15) * 4);
            }
#pragma unroll
            for (int t = 0; t < 4; ++t) {
                int f = tid + t * 256;
                pb[t] = *(const float4*)(Bm + (long)(kn + (f >> 4)) * ldb + col0 + (f & 15) * 4);
            }
        }
#pragma unroll
        for (int kk = 0; kk < BK; ++kk) {
            float ra[TM], rb[TN];
#pragma unroll
            for (int i = 0; i < TM; ++i) ra[i] = As[kk * LDA_S + ty * TM + i];
#pragma unroll
            for (int j = 0; j < TN; ++j) rb[j] = Bs[kk * LDB_S + tx * TN + j];
#pragma unroll
            for (int i = 0; i < TM; ++i)
#pragma unroll
                for (int j = 0; j < TN; ++j)
                    acc[i][j] = fmaf(ra[i], rb[j], acc[i][j]);
        }
    }

#pragma unroll
    for (int i = 0; i < TM; ++i) {
        int r = row0 + ty * TM + i;
        if (r >= M) continue;
#pragma unroll
        for (int j = 0; j < TN; ++j) {
            int c = col0 + tx * TN + j;
            float v = acc[i][j];
            if (flags & 1) v += bias[c];
            if (amode == 2) v += Add[(long)(((r >> 4) << 5) + (r & 15)) * ldc + c];
            C[(long)r * ldc + c] = v;
        }
    }
}

// Dual-job kernel: blocks [0,nA) run job A; blocks [nA, ...) compute
// SqOut = SqL @ SqR (512x512x512) for the A-power chain.
__global__ __launch_bounds__(256) void dual(
    const float* A, const float* Alast, const float* Bm, const float* bias,
    const float* Add, float* C, int M, int K, int lda, int ldb, int ldc,
    int flags, int amode, int nbxA, int nA,
    const float* SqL, const float* SqR, float* SqOut)
{
    __shared__ float sm[SMSZ];
    int j = blockIdx.x;
    if (j < nA)
        gemm_tile(sm, A, Alast, Bm, bias, Add, C, M, K, lda, ldb, ldc,
                  flags, amode, j % nbxA, j / nbxA);
    else {
        int s = j - nA;
        gemm_tile(sm, SqL, nullptr, SqR, nullptr, nullptr, SqOut,
                  H_, H_, H_, H_, H_, 0, 0, s % 8, s / 8);
    }
}

// ---------------------------------------------------------------------------
// z-partials split-K GEMM: BM=16, BN=64, BK=64, 256 threads.
// A = [V1nodes1..3 | x_last] (K=1664), B = [P32;P64;P96;Wr]
// Writes partials: zp[kc][16][H_], kc = blockIdx.x / 8.
// ---------------------------------------------------------------------------
#define TLDA 20
#define TLDB 68
#define TSM (64 * TLDA + 64 * TLDB)

__device__ __forceinline__ float4 z_a4(const float* __restrict__ V1,
                                       const float* __restrict__ x,
                                       int b, int gk) {
    int seg = gk >> 9;
    if (seg < 3)
        return *(const float4*)(V1 + (long)((seg + 1) * 16 + b) * H_ + (gk & 511));
    return *(const float4*)(x + ((long)b * T_ + (T_ - 1)) * L_ + (gk - 1536));
}

__device__ __forceinline__ float4 z_b4(const float* __restrict__ P32,
                                       const float* __restrict__ P64,
                                       const float* __restrict__ P96,
                                       const float* __restrict__ Wr,
                                       int kr, int c) {
    const float* p;
    if (kr < 512)       p = P32 + (long)kr * H_;
    else if (kr < 1024) p = P64 + (long)(kr - 512) * H_;
    else if (kr < 1536) p = P96 + (long)(kr - 1024) * H_;
    else                p = Wr + (long)(kr - 1536) * H_;
    return *(const float4*)(p + c);
}

__global__ __launch_bounds__(256) void zpart(
    const float* __restrict__ V1, const float* __restrict__ x,
    const float* __restrict__ P32, const float* __restrict__ P64,
    const float* __restrict__ P96, const float* __restrict__ Wr,
    float* __restrict__ zp)
{
    __shared__ float sm[TSM];
    float* As = sm;                    // [64][20] transposed (A[k][row])
    float* Bs = sm + 64 * TLDA;        // [64][68]
    const int tid = threadIdx.x;
    const int tx = tid & 15, ty = tid >> 4;      // ty = row 0..15
    const int kc = blockIdx.x >> 3;
    const int col0 = (blockIdx.x & 7) * 64;
    const int kOff = kc * 128;

    float4 pa, pb[4];
    pa = z_a4(V1, x, tid >> 4, kOff + (tid & 15) * 4);
#pragma unroll
    for (int t = 0; t < 4; ++t) {
        int f = tid + t * 256;
        pb[t] = z_b4(P32, P64, P96, Wr, kOff + (f >> 4), col0 + (f & 15) * 4);
    }

    float acc[4] = {};
    for (int k0 = kOff; k0 < kOff + 128; k0 += 64) {
        __syncthreads();
        {
            int arow = tid >> 4, kk = (tid & 15) * 4;
            As[(kk + 0) * TLDA + arow] = pa.x;
            As[(kk + 1) * TLDA + arow] = pa.y;
            As[(kk + 2) * TLDA + arow] = pa.z;
            As[(kk + 3) * TLDA + arow] = pa.w;
        }
#pragma unroll
        for (int t = 0; t < 4; ++t) {
            int f = tid + t * 256;
            *(float4*)&Bs[(f >> 4) * TLDB + (f & 15) * 4] = pb[t];
        }
        __syncthreads();
        int kn = k0 + 64;
        if (kn < kOff + 128) {
            pa = z_a4(V1, x, tid >> 4, kn + (tid & 15) * 4);
#pragma unroll
            for (int t = 0; t < 4; ++t) {
                int f = tid + t * 256;
                pb[t] = z_b4(P32, P64, P96, Wr, kn + (f >> 4), col0 + (f & 15) * 4);
            }
        }
#pragma unroll
        for (int kk = 0; kk < 64; ++kk) {
            float ra = As[kk * TLDA + ty];
            float4 rb = *(float4*)&Bs[kk * TLDB + tx * 4];
            acc[0] = fmaf(ra, rb.x, acc[0]);
            acc[1] = fmaf(ra, rb.y, acc[1]);
            acc[2] = fmaf(ra, rb.z, acc[2]);
            acc[3] = fmaf(ra, rb.w, acc[3]);
        }
    }

    float* dst = zp + (long)kc * 16 * H_ + (long)ty * H_ + col0 + tx * 4;
    *(float4*)dst = make_float4(acc[0], acc[1], acc[2], acc[3]);
}

// ---------------------------------------------------------------------------
// Fused zlnred + MLP1 partial GEMM.  grid = 64 (4 kc x 16 col tiles) — SAME
// width as the baseline tailgemm<1> it replaces (round-6 lesson: narrow grids
// are latency-bound; keep every grid wide).
// Phase 1: each block recomputes zn full-row LN stats (reads all 13 zp
// partials, ~425KB from L2, redundant-but-parallel) and keeps only its own
// 128-col K-slice in LDS (znS[16][132], padded -> conflict-free broadcast).
// Phase 2: h1p[kc] col tile = znS @ W1[kOff:kOff+128, col0:col0+64].
// Numerically identical to zlnred followed by tailgemm<1>.
// ---------------------------------------------------------------------------
__global__ __launch_bounds__(256) void zmlp1(
    const float* __restrict__ V1, const float* __restrict__ zp,
    const float* __restrict__ br, const float* __restrict__ lng,
    const float* __restrict__ lnb, const float* __restrict__ W1,
    float* __restrict__ h1p)
{
    __shared__ float znS[16][132];         // 8.4 KB (pad 132: ty*132%32=4*ty)
    __shared__ float Bs[64 * TLDB];        // 17.4 KB
    const int tid = threadIdx.x;
    const int kc   = blockIdx.x >> 4;      // 0..3  (K-chunk of 128)
    const int col0 = (blockIdx.x & 15) * 64;
    const int kOff = kc * 128;

    // ---- phase 1: z + LN stats; keep slice [kOff, kOff+128) ----
    {
        const int r = tid >> 4;            // row 0..15
        const int l = tid & 15;            // lane in row
        float4 keep0 = make_float4(0.f, 0.f, 0.f, 0.f);
        float4 keep1 = make_float4(0.f, 0.f, 0.f, 0.f);
        float s1 = 0.f, s2 = 0.f;
#pragma unroll
        for (int i = 0; i < 8; ++i) {
            int c = l * 4 + i * 64;
            float4 v = *(const float4*)(V1 + (long)r * H_ + c);   // node0
            float4 bb = *(const float4*)(br + c);
            v.x += bb.x; v.y += bb.y; v.z += bb.z; v.w += bb.w;
#pragma unroll
            for (int p = 0; p < 13; ++p) {
                float4 q = *(const float4*)(zp + (long)p * 16 * H_ + (long)r * H_ + c);
                v.x += q.x; v.y += q.y; v.z += q.z; v.w += q.w;
            }
            s1 += v.x + v.y + v.z + v.w;
            s2 += v.x * v.x + v.y * v.y + v.z * v.z + v.w * v.w;
            if (i == (kc << 1))     keep0 = v;
            if (i == (kc << 1) + 1) keep1 = v;
        }
        // reduce across the 16 lanes of this row (lane-group aligned)
#pragma unroll
        for (int off = 1; off < 16; off <<= 1) {
            s1 += __shfl_xor(s1, off, 64);
            s2 += __shfl_xor(s2, off, 64);
        }
        float mu  = s1 * (1.0f / H_);
        float var = s2 * (1.0f / H_) - mu * mu;
        float rs  = rsqrtf(var + EPS);

        int c0 = kOff + l * 4;             // global col of keep0
        float4 g0 = *(const float4*)(lng + c0);
        float4 t0 = *(const float4*)(lnb + c0);
        keep0.x = (keep0.x - mu) * rs * g0.x + t0.x;
        keep0.y = (keep0.y - mu) * rs * g0.y + t0.y;
        keep0.z = (keep0.z - mu) * rs * g0.z + t0.z;
        keep0.w = (keep0.w - mu) * rs * g0.w + t0.w;
        int c1 = c0 + 64;
        float4 g1 = *(const float4*)(lng + c1);
        float4 t1 = *(const float4*)(lnb + c1);
        keep1.x = (keep1.x - mu) * rs * g1.x + t1.x;
        keep1.y = (keep1.y - mu) * rs * g1.y + t1.y;
        keep1.z = (keep1.z - mu) * rs * g1.z + t1.z;
        keep1.w = (keep1.w - mu) * rs * g1.w + t1.w;

        znS[r][l * 4 + 0] = keep0.x; znS[r][l * 4 + 1] = keep0.y;
        znS[r][l * 4 + 2] = keep0.z; znS[r][l * 4 + 3] = keep0.w;
        znS[r][64 + l * 4 + 0] = keep1.x; znS[r][64 + l * 4 + 1] = keep1.y;
        znS[r][64 + l * 4 + 2] = keep1.z; znS[r][64 + l * 4 + 3] = keep1.w;
    }

    // ---- phase 2: h1p[kc] tile = znS @ W1 slice, kLen = 128 ----
    const int tx = tid & 15, ty = tid >> 4;
    float4 pb[4];
#pragma unroll
    for (int t = 0; t < 4; ++t) {
        int f = tid + t * 256;
        pb[t] = *(const float4*)(W1 + (long)(kOff + (f >> 4)) * F_ + col0 + (f & 15) * 4);
    }
    float acc[4] = {};
    for (int k0 = 0; k0 < 128; k0 += 64) {
        __syncthreads();               // also covers phase-1 znS writes
#pragma unroll
        for (int t = 0; t < 4; ++t) {
            int f = tid + t * 256;
            *(float4*)&Bs[(f >> 4) * TLDB + (f & 15) * 4] = pb[t];
        }
        __syncthreads();
        if (k0 == 0) {
#pragma unroll
            for (int t = 0; t < 4; ++t) {
                int f = tid + t * 256;
                pb[t] = *(const float4*)(W1 + (long)(kOff + 64 + (f >> 4)) * F_ + col0 + (f & 15) * 4);
            }
        }
#pragma unroll
        for (int kk = 0; kk < 64; ++kk) {
            float ra = znS[ty][k0 + kk];       // broadcast across tx lanes
            float4 rb = *(float4*)&Bs[kk * TLDB + tx * 4];
            acc[0] = fmaf(ra, rb.x, acc[0]);
            acc[1] = fmaf(ra, rb.y, acc[1]);
            acc[2] = fmaf(ra, rb.z, acc[2]);
            acc[3] = fmaf(ra, rb.w, acc[3]);
        }
    }
    float* dst = h1p + (long)kc * 16 * F_ + (long)ty * F_ + col0 + tx * 4;
    *(float4*)dst = make_float4(acc[0], acc[1], acc[2], acc[3]);
}

// ---------------------------------------------------------------------------
// Fused hred + MLP2 partial GEMM.  grid = 64 (8 kc x 8 col tiles) — SAME
// width as baseline tailgemm<2>.  A-operand = relu(b1 + sum_4 h1p) computed
// on the fly (5 float4 L2 reads per A float4).  Writes op[kc][16][H_].
// Numerically identical to hred followed by tailgemm<2>.
// ---------------------------------------------------------------------------
__device__ __forceinline__ float4 hid_a4(const float* __restrict__ h1p,
                                         const float* __restrict__ b1,
                                         int b, int gk) {
    float4 v = *(const float4*)(b1 + gk);
#pragma unroll
    for (int p = 0; p < 4; ++p) {
        float4 q = *(const float4*)(h1p + (long)p * 16 * F_ + (long)b * F_ + gk);
        v.x += q.x; v.y += q.y; v.z += q.z; v.w += q.w;
    }
    v.x = fmaxf(v.x, 0.f); v.y = fmaxf(v.y, 0.f);
    v.z = fmaxf(v.z, 0.f); v.w = fmaxf(v.w, 0.f);
    return v;
}

__global__ __launch_bounds__(256) void hmlp2(
    const float* __restrict__ h1p, const float* __restrict__ b1,
    const float* __restrict__ W2, float* __restrict__ op)
{
    __shared__ float sm[TSM];
    float* As = sm;                    // [64][20]
    float* Bs = sm + 64 * TLDA;        // [64][68]
    const int tid = threadIdx.x;
    const int tx = tid & 15, ty = tid >> 4;
    const int kc = blockIdx.x >> 3;           // 0..7 (K-chunk of 128 over 1024)
    const int col0 = (blockIdx.x & 7) * 64;
    const int kOff = kc * 128;

    float4 pa, pb[4];
    pa = hid_a4(h1p, b1, tid >> 4, kOff + (tid & 15) * 4);
#pragma unroll
    for (int t = 0; t < 4; ++t) {
        int f = tid + t * 256;
        pb[t] = *(const float4*)(W2 + (long)(kOff + (f >> 4)) * H_ + col0 + (f & 15) * 4);
    }

    float acc[4] = {};
    for (int k0 = kOff; k0 < kOff + 128; k0 += 64) {
        __syncthreads();
        {
            int arow = tid >> 4, kk = (tid & 15) * 4;
            As[(kk + 0) * TLDA + arow] = pa.x;
            As[(kk + 1) * TLDA + arow] = pa.y;
            As[(kk + 2) * TLDA + arow] = pa.z;
            As[(kk + 3) * TLDA + arow] = pa.w;
        }
#pragma unroll
        for (int t = 0; t < 4; ++t) {
            int f = tid + t * 256;
            *(float4*)&Bs[(f >> 4) * TLDB + (f & 15) * 4] = pb[t];
        }
        __syncthreads();
        int kn = k0 + 64;
        if (kn < kOff + 128) {
            pa = hid_a4(h1p, b1, tid >> 4, kn + (tid & 15) * 4);
#pragma unroll
            for (int t = 0; t < 4; ++t) {
                int f = tid + t * 256;
                pb[t] = *(const float4*)(W2 + (long)(kn + (f >> 4)) * H_ + col0 + (f & 15) * 4);
            }
        }
#pragma unroll
        for (int kk = 0; kk < 64; ++kk) {
            float ra = As[kk * TLDA + ty];
            float4 rb = *(float4*)&Bs[kk * TLDB + tx * 4];
            acc[0] = fmaf(ra, rb.x, acc[0]);
            acc[1] = fmaf(ra, rb.y, acc[1]);
            acc[2] = fmaf(ra, rb.z, acc[2]);
            acc[3] = fmaf(ra, rb.w, acc[3]);
        }
    }

    float* dst = op + (long)kc * 16 * H_ + (long)ty * H_ + col0 + tx * 4;
    *(float4*)dst = make_float4(acc[0], acc[1], acc[2], acc[3]);
}

// out = b2 + sum_{kc<8} op[kc]   grid=32
__global__ __launch_bounds__(256) void ored(
    const float* __restrict__ op, const float* __restrict__ b2,
    float* __restrict__ out)
{
    int b = blockIdx.x >> 1;
    int c = (blockIdx.x & 1) * 256 + threadIdx.x;
    float s = b2[c];
#pragma unroll
    for (int kc = 0; kc < 8; ++kc)
        s += op[(long)kc * 16 * H_ + (long)b * H_ + c];
    out[(long)b * H_ + c] = s;
}

// ---------------------------------------------------------------------------
// 11-launch pipeline.  Round-6 lesson: keep every grid wide (>=64 blocks);
// fuse only where width is preserved.  Power chain depth-7 is structural.
// ---------------------------------------------------------------------------
extern "C" void kernel_launch(void* const* d_in, const int* in_sizes, int n_in,
                              void* d_out, int out_size, void* d_ws, size_t ws_size,
                              hipStream_t stream) {
    const float* x    = (const float*)d_in[0];
    const float* We   = (const float*)d_in[1];
    const float* be   = (const float*)d_in[2];
    const float* Wb   = (const float*)d_in[3];
    const float* Amat = (const float*)d_in[4];
    const float* Wr   = (const float*)d_in[5];
    const float* br   = (const float*)d_in[6];
    const float* lng  = (const float*)d_in[7];
    const float* lnb  = (const float*)d_in[8];
    const float* W1   = (const float*)d_in[9];
    const float* b1   = (const float*)d_in[10];
    const float* W2   = (const float*)d_in[11];
    const float* b2   = (const float*)d_in[12];
    float* out = (float*)d_out;

    float* ws  = (float*)d_ws;
    float* Wc  = ws;                         // 129 x 512
    float* V0  = Wc + 129 * H_;              // 2048 x 512
    float* V1  = V0 + 2048 * H_;             // 1024 x 512
    float* P2  = V1 + 1024 * H_;             // A^2
    float* P4  = P2 + H_ * H_;               // A^4
    float* P8  = P4 + H_ * H_;               // A^8
    float* P16 = P8 + H_ * H_;               // A^16
    float* P32 = P16 + H_ * H_;              // A^32
    float* P64 = P32 + H_ * H_;              // A^64
    float* P96 = P64 + H_ * H_;              // A^96
    float* zp  = P96 + H_ * H_;              // 13 x 16 x 512
    float* h1p = zp + 13 * B_ * H_;          // 4 x 16 x 1024
    float* op  = h1p + 4 * B_ * F_;          // 8 x 16 x 512

    // K0: Wc = [We;be]@Wb (129x512,K=256) [40] || A^2 [128]
    dual<<<168, 256, 0, stream>>>(We, be, Wb, nullptr, nullptr, Wc,
                                  129, M_, M_, H_, H_, 0, 3, 8, 40,
                                  Amat, Amat, P2);
    // K1: V0 = gather(x)@Wc + bc (2048x512,K=128) [512] || A^4 [128]
    dual<<<640, 256, 0, stream>>>(x, nullptr, Wc, Wc + 128 * H_, nullptr, V0,
                                  2048, L_, L_, H_, H_, 1, 1, 8, 512,
                                  P2, P2, P4);
    // K2 (l1): V1 = comb(V0, A), 1024 rows [256] || A^8 [128]
    dual<<<384, 256, 0, stream>>>(V0, nullptr, Amat, nullptr, V0, V1,
                                  1024, H_, H_, H_, H_, 0, 2, 8, 256,
                                  P4, P4, P8);
    // K3 (l2): V0 = comb(V1, A^2), 512 rows [128] || A^16 [128]
    dual<<<256, 256, 0, stream>>>(V1, nullptr, P2, nullptr, V1, V0,
                                  512, H_, H_, H_, H_, 0, 2, 8, 128,
                                  P8, P8, P16);
    // K4 (l3): V1 = comb(V0, A^4), 256 rows [64] || A^32 [128]
    dual<<<192, 256, 0, stream>>>(V0, nullptr, P4, nullptr, V0, V1,
                                  256, H_, H_, H_, H_, 0, 2, 8, 64,
                                  P16, P16, P32);
    // K5 (l4): V0 = comb(V1, A^8), 128 rows [32] || A^64 [128]
    dual<<<160, 256, 0, stream>>>(V1, nullptr, P8, nullptr, V1, V0,
                                  128, H_, H_, H_, H_, 0, 2, 8, 32,
                                  P32, P32, P64);
    // K6 (l5): V1 = comb(V0, A^16), 64 rows (4 nodes) [16] || A^96 [128]
    dual<<<144, 256, 0, stream>>>(V0, nullptr, P16, nullptr, V0, V1,
                                  64, H_, H_, H_, H_, 0, 2, 8, 16,
                                  P32, P64, P96);
    // K7: z-partials (K=1664, 13 chunks x 8 col tiles)
    zpart<<<104, 256, 0, stream>>>(V1, x, P32, P64, P96, Wr, zp);
    // K8: fused z-reduce+LN (per-block recompute) + MLP1 partials
    zmlp1<<<64, 256, 0, stream>>>(V1, zp, br, lng, lnb, W1, h1p);
    // K9: fused relu-reduce + MLP2 partials
    hmlp2<<<64, 256, 0, stream>>>(h1p, b1, W2, op);
    // K10: reduce -> out
    ored<<<32, 256, 0, stream>>>(op, b2, out);
}

// Round 8
// 284.464 us; speedup vs baseline: 7.0142x; 1.0246x over previous
//
#include <hip/hip_runtime.h>

#define B_  16
#define T_  2048
#define L_  128
#define M_  256
#define H_  512
#define F_  1024
#define EPS 1e-5f

// LDS: As[64][36] + Bs[64][68] = 6656 floats = 26624 B  (2 blocks/CU)
#define LDA_S 36
#define LDB_S 68
#define SMSZ (64 * LDA_S + 64 * LDB_S)

// ---------------------------------------------------------------------------
// A-operand load with source remap.
// amode: 0 = row-major(lda); 1 = gather x[b=r&15][T-1-(r>>4)][:];
//        2 = tree (row -> vin[((r>>4)<<5)+16+(r&15)]);
//        3 = rows 0..M-2 from A, row M-1 from Alast
// ---------------------------------------------------------------------------
__device__ __forceinline__ float4 load_a4(const float* __restrict__ A,
                                          const float* __restrict__ Alast,
                                          int M, int lda, int amode,
                                          int gr, int gk) {
    float4 av = make_float4(0.f, 0.f, 0.f, 0.f);
    if (gr < M) {
        const float* p;
        if (amode == 1)
            p = A + (long)((gr & 15) * T_ + (T_ - 1 - (gr >> 4))) * L_ + gk;
        else if (amode == 2)
            p = A + (long)(((gr >> 4) << 5) + 16 + (gr & 15)) * lda + gk;
        else if (amode == 3 && gr == M - 1)
            p = Alast + gk;
        else
            p = A + (long)gr * lda + gk;
        av = *(const float4*)p;
    }
    return av;
}

// ---------------------------------------------------------------------------
// 32x64 tile GEMM, BK=64, TM=2 TN=4, 256 threads, reg-prefetch pipeline.
// flags: 1 = +bias[c].  amode==2 epilogue adds Add[((r>>4)<<5)+(r&15)].
// ---------------------------------------------------------------------------
__device__ __forceinline__ void gemm_tile(
    float* sm,
    const float* __restrict__ A, const float* __restrict__ Alast,
    const float* __restrict__ Bm, const float* __restrict__ bias,
    const float* __restrict__ Add, float* __restrict__ C,
    int M, int K, int lda, int ldb, int ldc,
    int flags, int amode, int bx, int by)
{
    constexpr int BM = 32, BN = 64, BK = 64, TM = 2, TN = 4;
    float* As = sm;                    // [64][36] transposed A tile
    float* Bs = sm + BK * LDA_S;       // [64][68]
    const int tid = threadIdx.x;
    const int tx = tid & 15;           // BN/TN = 16
    const int ty = tid >> 4;           // 0..15
    const int row0 = by * BM, col0 = bx * BN;

    float4 pa[2], pb[4];
#pragma unroll
    for (int t = 0; t < 2; ++t) {
        int f = tid + t * 256;
        pa[t] = load_a4(A, Alast, M, lda, amode, row0 + (f >> 4), (f & 15) * 4);
    }
#pragma unroll
    for (int t = 0; t < 4; ++t) {
        int f = tid + t * 256;
        pb[t] = *(const float4*)(Bm + (long)(f >> 4) * ldb + col0 + (f & 15) * 4);
    }

    float acc[TM][TN] = {};

    for (int k0 = 0; k0 < K; k0 += BK) {
        __syncthreads();               // prior compute done reading LDS
#pragma unroll
        for (int t = 0; t < 2; ++t) {
            int f = tid + t * 256;
            int arow = f >> 4, kk = (f & 15) * 4;
            As[(kk + 0) * LDA_S + arow] = pa[t].x;
            As[(kk + 1) * LDA_S + arow] = pa[t].y;
            As[(kk + 2) * LDA_S + arow] = pa[t].z;
            As[(kk + 3) * LDA_S + arow] = pa[t].w;
        }
#pragma unroll
        for (int t = 0; t < 4; ++t) {
            int f = tid + t * 256;
            *(float4*)&Bs[(f >> 4) * LDB_S + (f & 15) * 4] = pb[t];
        }
        __syncthreads();
        int kn = k0 + BK;
        if (kn < K) {                  // prefetch next tiles; in flight during FMAs
#pragma unroll
            for (int t = 0; t < 2; ++t) {
                int f = tid + t * 256;
                pa[t] = load_a4(A, Alast, M, lda, amode, row0 + (f >> 4), kn + (f & 15) * 4);
            }
#pragma unroll
            for (int t = 0; t < 4; ++t) {
                int f = tid + t * 256;
                pb[t] = *(const float4*)(Bm + (long)(kn + (f >> 4)) * ldb + col0 + (f & 15) * 4);
            }
        }
#pragma unroll
        for (int kk = 0; kk < BK; ++kk) {
            float ra[TM], rb[TN];
#pragma unroll
            for (int i = 0; i < TM; ++i) ra[i] = As[kk * LDA_S + ty * TM + i];
#pragma unroll
            for (int j = 0; j < TN; ++j) rb[j] = Bs[kk * LDB_S + tx * TN + j];
#pragma unroll
            for (int i = 0; i < TM; ++i)
#pragma unroll
                for (int j = 0; j < TN; ++j)
                    acc[i][j] = fmaf(ra[i], rb[j], acc[i][j]);
        }
    }

#pragma unroll
    for (int i = 0; i < TM; ++i) {
        int r = row0 + ty * TM + i;
        if (r >= M) continue;
#pragma unroll
        for (int j = 0; j < TN; ++j) {
            int c = col0 + tx * TN + j;
            float v = acc[i][j];
            if (flags & 1) v += bias[c];
            if (amode == 2) v += Add[(long)(((r >> 4) << 5) + (r & 15)) * ldc + c];
            C[(long)r * ldc + c] = v;
        }
    }
}

// Dual-job kernel: blocks [0,nA) run job A; blocks [nA, ...) compute
// SqOut = SqL @ SqR (512x512x512) for the A-power chain.
__global__ __launch_bounds__(256) void dual(
    const float* A, const float* Alast, const float* Bm, const float* bias,
    const float* Add, float* C, int M, int K, int lda, int ldb, int ldc,
    int flags, int amode, int nbxA, int nA,
    const float* SqL, const float* SqR, float* SqOut)
{
    __shared__ float sm[SMSZ];
    int j = blockIdx.x;
    if (j < nA)
        gemm_tile(sm, A, Alast, Bm, bias, Add, C, M, K, lda, ldb, ldc,
                  flags, amode, j % nbxA, j / nbxA);
    else {
        int s = j - nA;
        gemm_tile(sm, SqL, nullptr, SqR, nullptr, nullptr, SqOut,
                  H_, H_, H_, H_, H_, 0, 0, s % 8, s / 8);
    }
}

// ---------------------------------------------------------------------------
// Tail split-K GEMM: BM=16, BN=64, BK=64, 256 threads, 4 outputs/thread.
// MODE 0: z-GEMM  A = [V1nodes1..3 | x_last] (K=1664), B = [P32;P64;P96;Wr]
// MODE 1: MLP1    A = zn (16x512),  B = W1 (512x1024)
// MODE 2: MLP2    A = hid (16x1024), B = W2 (1024x512)
// Writes partials: parts[kc][16][LDC], kc = blockIdx.x / nbx.
// ---------------------------------------------------------------------------
#define TLDA 20
#define TLDB 68
#define TSM (64 * TLDA + 64 * TLDB)

template <int MODE>
__device__ __forceinline__ float4 tail_a4(const float* __restrict__ Asrc,
                                          const float* __restrict__ x,
                                          int b, int gk) {
    if (MODE == 0) {
        int seg = gk >> 9;
        if (seg < 3)
            return *(const float4*)(Asrc + (long)((seg + 1) * 16 + b) * H_ + (gk & 511));
        return *(const float4*)(x + ((long)b * T_ + (T_ - 1)) * L_ + (gk - 1536));
    } else if (MODE == 1) {
        return *(const float4*)(Asrc + (long)b * H_ + gk);
    } else {
        return *(const float4*)(Asrc + (long)b * F_ + gk);
    }
}

template <int MODE>
__device__ __forceinline__ float4 tail_b4(const float* __restrict__ P32,
                                          const float* __restrict__ P64,
                                          const float* __restrict__ P96,
                                          const float* __restrict__ WrB,
                                          int kr, int c) {
    if (MODE == 0) {
        const float* p;
        if (kr < 512)       p = P32 + (long)kr * H_;
        else if (kr < 1024) p = P64 + (long)(kr - 512) * H_;
        else if (kr < 1536) p = P96 + (long)(kr - 1024) * H_;
        else                p = WrB + (long)(kr - 1536) * H_;
        return *(const float4*)(p + c);
    } else if (MODE == 1) {
        return *(const float4*)(WrB + (long)kr * F_ + c);
    } else {
        return *(const float4*)(WrB + (long)kr * H_ + c);
    }
}

template <int MODE>
__global__ __launch_bounds__(256) void tailgemm(
    const float* __restrict__ Asrc, const float* __restrict__ x,
    const float* __restrict__ P32, const float* __restrict__ P64,
    const float* __restrict__ P96, const float* __restrict__ WrB,
    float* __restrict__ parts, int nbx, int kLen)
{
    constexpr int LDC = (MODE == 1) ? F_ : H_;
    __shared__ float sm[TSM];
    float* As = sm;                    // [64][20] transposed (A[k][row])
    float* Bs = sm + 64 * TLDA;        // [64][68]
    const int tid = threadIdx.x;
    const int tx = tid & 15, ty = tid >> 4;      // ty = row 0..15
    const int kc = blockIdx.x / nbx;
    const int col0 = (blockIdx.x % nbx) * 64;
    const int kOff = kc * kLen;

    float4 pa, pb[4];
    {
        int gk = kOff + (tid & 15) * 4;
        pa = tail_a4<MODE>(Asrc, x, tid >> 4, gk);
#pragma unroll
        for (int t = 0; t < 4; ++t) {
            int f = tid + t * 256;
            pb[t] = tail_b4<MODE>(P32, P64, P96, WrB, kOff + (f >> 4), col0 + (f & 15) * 4);
        }
    }

    float acc[4] = {};
    for (int k0 = kOff; k0 < kOff + kLen; k0 += 64) {
        __syncthreads();
        {
            int arow = tid >> 4, kk = (tid & 15) * 4;
            As[(kk + 0) * TLDA + arow] = pa.x;
            As[(kk + 1) * TLDA + arow] = pa.y;
            As[(kk + 2) * TLDA + arow] = pa.z;
            As[(kk + 3) * TLDA + arow] = pa.w;
        }
#pragma unroll
        for (int t = 0; t < 4; ++t) {
            int f = tid + t * 256;
            *(float4*)&Bs[(f >> 4) * TLDB + (f & 15) * 4] = pb[t];
        }
        __syncthreads();
        int kn = k0 + 64;
        if (kn < kOff + kLen) {
            pa = tail_a4<MODE>(Asrc, x, tid >> 4, kn + (tid & 15) * 4);
#pragma unroll
            for (int t = 0; t < 4; ++t) {
                int f = tid + t * 256;
                pb[t] = tail_b4<MODE>(P32, P64, P96, WrB, kn + (f >> 4), col0 + (f & 15) * 4);
            }
        }
#pragma unroll
        for (int kk = 0; kk < 64; ++kk) {
            float ra = As[kk * TLDA + ty];
            float4 rb = *(float4*)&Bs[kk * TLDB + tx * 4];
            acc[0] = fmaf(ra, rb.x, acc[0]);
            acc[1] = fmaf(ra, rb.y, acc[1]);
            acc[2] = fmaf(ra, rb.z, acc[2]);
            acc[3] = fmaf(ra, rb.w, acc[3]);
        }
    }

    float* dst = parts + (long)kc * 16 * LDC + (long)ty * LDC + col0 + tx * 4;
    *(float4*)dst = make_float4(acc[0], acc[1], acc[2], acc[3]);
}

// z = node0 + br + sum(zparts); LayerNorm -> zn.  grid=16 (one block / batch)
__global__ __launch_bounds__(256) void zlnred(
    const float* __restrict__ V1, const float* __restrict__ zparts,
    const float* __restrict__ br, const float* __restrict__ lng,
    const float* __restrict__ lnb, float* __restrict__ zn)
{
    __shared__ float red1[4], red2[4];
    const int b = blockIdx.x, tid = threadIdx.x;
    float z[2];
#pragma unroll
    for (int jj = 0; jj < 2; ++jj) {
        int c = tid + jj * 256;
        float s = V1[(long)b * H_ + c] + br[c];      // node0 row
#pragma unroll
        for (int kc = 0; kc < 13; ++kc)
            s += zparts[(long)kc * 16 * H_ + (long)b * H_ + c];
        z[jj] = s;
    }
    float s1 = z[0] + z[1];
    float s2 = z[0] * z[0] + z[1] * z[1];
#pragma unroll
    for (int off = 32; off > 0; off >>= 1) {
        s1 += __shfl_down(s1, off, 64);
        s2 += __shfl_down(s2, off, 64);
    }
    int wid = tid >> 6, lane = tid & 63;
    if (lane == 0) { red1[wid] = s1; red2[wid] = s2; }
    __syncthreads();
    float S1 = red1[0] + red1[1] + red1[2] + red1[3];
    float S2 = red2[0] + red2[1] + red2[2] + red2[3];
    float mu  = S1 * (1.0f / H_);
    float var = S2 * (1.0f / H_) - mu * mu;
    float rs  = rsqrtf(var + EPS);
#pragma unroll
    for (int jj = 0; jj < 2; ++jj) {
        int c = tid + jj * 256;
        zn[(long)b * H_ + c] = (z[jj] - mu) * rs * lng[c] + lnb[c];
    }
}

// hid = relu(b1 + sum_{kc<4} h1p[kc])   grid=64
__global__ __launch_bounds__(256) void hred(
    const float* __restrict__ h1p, const float* __restrict__ b1,
    float* __restrict__ hid)
{
    int b = blockIdx.x >> 2;
    int c = (blockIdx.x & 3) * 256 + threadIdx.x;
    float s = b1[c];
#pragma unroll
    for (int kc = 0; kc < 4; ++kc)
        s += h1p[(long)kc * 16 * F_ + (long)b * F_ + c];
    hid[(long)b * F_ + c] = fmaxf(s, 0.f);
}

// out = b2 + sum_{kc<8} op[kc]   grid=32
__global__ __launch_bounds__(256) void ored(
    const float* __restrict__ op, const float* __restrict__ b2,
    float* __restrict__ out)
{
    int b = blockIdx.x >> 1;
    int c = (blockIdx.x & 1) * 256 + threadIdx.x;
    float s = b2[c];
#pragma unroll
    for (int kc = 0; kc < 8; ++kc)
        s += op[(long)kc * 16 * H_ + (long)b * H_ + c];
    out[(long)b * H_ + c] = s;
}

// ---------------------------------------------------------------------------
// Best-measured variant (R0, 284.9us).  Session findings:
//  - Pipeline is overhead-bound: busy ~50-80us, rest is fixed harness/launch
//    cost.  13 vs 11 launches is sub-noise (284.9 vs 291.5); 10-launch with
//    narrow (<64-block) tail kernels regresses (+42us, latency-bound grids).
//  - In-kernel grid sync on this 8-XCD chip costs 70-160us/barrier across 4
//    protocols (cg, flat, 2-level, broadcast tree) -> persistent-kernel
//    variants run 3-7x slower.  Multi-queue event overlap forbidden by
//    harness (no hipEvent* under graph capture).
//  - A-power chain (A^2..A^96) is depth-7 by the doubling bound; tree and
//    chain co-scheduled in every dual stage; structural launch floor = 11.
// ---------------------------------------------------------------------------
extern "C" void kernel_launch(void* const* d_in, const int* in_sizes, int n_in,
                              void* d_out, int out_size, void* d_ws, size_t ws_size,
                              hipStream_t stream) {
    const float* x    = (const float*)d_in[0];
    const float* We   = (const float*)d_in[1];
    const float* be   = (const float*)d_in[2];
    const float* Wb   = (const float*)d_in[3];
    const float* Amat = (const float*)d_in[4];
    const float* Wr   = (const float*)d_in[5];
    const float* br   = (const float*)d_in[6];
    const float* lng  = (const float*)d_in[7];
    const float* lnb  = (const float*)d_in[8];
    const float* W1   = (const float*)d_in[9];
    const float* b1   = (const float*)d_in[10];
    const float* W2   = (const float*)d_in[11];
    const float* b2   = (const float*)d_in[12];
    float* out = (float*)d_out;

    float* ws  = (float*)d_ws;
    float* Wc  = ws;                         // 129 x 512
    float* V0  = Wc + 129 * H_;              // 2048 x 512
    float* V1  = V0 + 2048 * H_;             // 1024 x 512
    float* P2  = V1 + 1024 * H_;             // A^2
    float* P4  = P2 + H_ * H_;               // A^4
    float* P8  = P4 + H_ * H_;               // A^8
    float* P16 = P8 + H_ * H_;               // A^16
    float* P32 = P16 + H_ * H_;              // A^32
    float* P64 = P32 + H_ * H_;              // A^64
    float* P96 = P64 + H_ * H_;              // A^96
    float* zn  = P96 + H_ * H_;              // 16 x 512
    float* hid = zn + B_ * H_;               // 16 x 1024
    float* zp  = hid + B_ * F_;              // 13 x 16 x 512
    float* h1p = zp + 13 * B_ * H_;          // 4 x 16 x 1024
    float* op  = h1p + 4 * B_ * F_;          // 8 x 16 x 512

    // K0: Wc = [We;be]@Wb (129x512,K=256) [40] || A^2 [128]
    dual<<<168, 256, 0, stream>>>(We, be, Wb, nullptr, nullptr, Wc,
                                  129, M_, M_, H_, H_, 0, 3, 8, 40,
                                  Amat, Amat, P2);
    // K1: V0 = gather(x)@Wc + bc (2048x512,K=128) [512] || A^4 [128]
    dual<<<640, 256, 0, stream>>>(x, nullptr, Wc, Wc + 128 * H_, nullptr, V0,
                                  2048, L_, L_, H_, H_, 1, 1, 8, 512,
                                  P2, P2, P4);
    // K2 (l1): V1 = comb(V0, A), 1024 rows [256] || A^8 [128]
    dual<<<384, 256, 0, stream>>>(V0, nullptr, Amat, nullptr, V0, V1,
                                  1024, H_, H_, H_, H_, 0, 2, 8, 256,
                                  P4, P4, P8);
    // K3 (l2): V0 = comb(V1, A^2), 512 rows [128] || A^16 [128]
    dual<<<256, 256, 0, stream>>>(V1, nullptr, P2, nullptr, V1, V0,
                                  512, H_, H_, H_, H_, 0, 2, 8, 128,
                                  P8, P8, P16);
    // K4 (l3): V1 = comb(V0, A^4), 256 rows [64] || A^32 [128]
    dual<<<192, 256, 0, stream>>>(V0, nullptr, P4, nullptr, V0, V1,
                                  256, H_, H_, H_, H_, 0, 2, 8, 64,
                                  P16, P16, P32);
    // K5 (l4): V0 = comb(V1, A^8), 128 rows [32] || A^64 [128]
    dual<<<160, 256, 0, stream>>>(V1, nullptr, P8, nullptr, V1, V0,
                                  128, H_, H_, H_, H_, 0, 2, 8, 32,
                                  P32, P32, P64);
    // K6 (l5): V1 = comb(V0, A^16), 64 rows (4 nodes) [16] || A^96 = A^32*A^64 [128]
    dual<<<144, 256, 0, stream>>>(V0, nullptr, P16, nullptr, V0, V1,
                                  64, H_, H_, H_, H_, 0, 2, 8, 16,
                                  P32, P64, P96);
    // K7: z-partials (K=1664, 13 chunks x 8 col tiles)
    tailgemm<0><<<104, 256, 0, stream>>>(V1, x, P32, P64, P96, Wr, zp, 8, 128);
    // K7b: z reduce + LayerNorm -> zn
    zlnred<<<16, 256, 0, stream>>>(V1, zp, br, lng, lnb, zn);
    // K8: MLP1 partials (K=512, 4 chunks x 16 col tiles)
    tailgemm<1><<<64, 256, 0, stream>>>(zn, nullptr, nullptr, nullptr, nullptr,
                                        W1, h1p, 16, 128);
    // K8b: relu-reduce -> hid
    hred<<<64, 256, 0, stream>>>(h1p, b1, hid);
    // K9: MLP2 partials (K=1024, 8 chunks x 8 col tiles)
    tailgemm<2><<<64, 256, 0, stream>>>(hid, nullptr, nullptr, nullptr, nullptr,
                                        W2, op, 8, 128);
    // K9b: reduce -> out
    ored<<<32, 256, 0, stream>>>(op, b2, out);
}